// Round 3
// baseline (621.800 us; speedup 1.0000x reference)
//
#include <hip/hip_runtime.h>

#define NN 10000
#define EE 160000
#define MAXDEG 256

typedef __attribute__((ext_vector_type(8))) short bf16x8;
typedef __attribute__((ext_vector_type(4))) float f32x4;

__device__ __forceinline__ float b2f(unsigned short s) {
    union { unsigned u; float f; } v; v.u = ((unsigned)s) << 16; return v.f;
}
__device__ __forceinline__ short f2b(float f) {
    union { float f; unsigned u; } v; v.f = f;
    unsigned r = v.u + 0x7FFF + ((v.u >> 16) & 1);  // RNE
    return (short)(r >> 16);
}

// ---------------------------------------------------------------- CSR build
__global__ __launch_bounds__(256) void hist_kernel(const int* __restrict__ dst,
                                                   int* __restrict__ counts, int E) {
    int e = blockIdx.x * 256 + threadIdx.x;
    if (e < E) atomicAdd(&counts[dst[e]], 1);
}

__global__ __launch_bounds__(256) void scan_kernel(const int* __restrict__ counts,
                                                   int* __restrict__ off,
                                                   int* __restrict__ cur, int n) {
    __shared__ int part[256];
    int tid = threadIdx.x;
    int chunk = (n + 255) / 256;
    int lo = tid * chunk; if (lo > n) lo = n;
    int hi = lo + chunk;  if (hi > n) hi = n;
    int s = 0;
    for (int i = lo; i < hi; ++i) s += counts[i];
    part[tid] = s;
    __syncthreads();
    for (int o = 1; o < 256; o <<= 1) {
        int v = (tid >= o) ? part[tid - o] : 0;
        __syncthreads();
        part[tid] += v;
        __syncthreads();
    }
    int run = (tid == 0) ? 0 : part[tid - 1];
    for (int i = lo; i < hi; ++i) { off[i] = run; cur[i] = run; run += counts[i]; }
    if (tid == 255) off[n] = part[255];
}

__global__ __launch_bounds__(256) void fill_kernel(const int* __restrict__ src,
                                                   const int* __restrict__ dst,
                                                   int* __restrict__ cur,
                                                   int* __restrict__ ssrc,
                                                   int* __restrict__ poe, int E) {
    int e = blockIdx.x * 256 + threadIdx.x;
    if (e < E) {
        int p = atomicAdd(&cur[dst[e]], 1);
        ssrc[p] = src[e];
        poe[e] = p;
    }
}

// ---------------------------------------------------------------- casts
__global__ __launch_bounds__(256) void cast_f2b_k(const float* __restrict__ x,
                                                  short* __restrict__ y, int n) {
    int t = blockIdx.x * 256 + threadIdx.x;
    if (t < n) y[t] = f2b(x[t]);
}

// all 8 weight transposes (K=128) in one launch
struct TParams {
    const float* src[8];
    short* dst[8];
    int N[8];
    int cum[9];
};
__global__ __launch_bounds__(256) void transpose_all(TParams P) {
    int t = blockIdx.x * 256 + threadIdx.x;
    if (t >= P.cum[8]) return;
    int i = 0;
    #pragma unroll
    for (int j = 1; j < 8; ++j) i += (t >= P.cum[j]);
    int local = t - P.cum[i];
    int n = local >> 7, k = local & 127;
    P.dst[i][local] = f2b(P.src[i][(size_t)k * P.N[i] + n]);
}

// ------------------------------------------------- v[i,h] = sum_d We[i,h,d]*ae[h,d]
__global__ void compute_v(const float* __restrict__ We, const float* __restrict__ ae,
                          float* __restrict__ v) {
    int t = threadIdx.x;        // 256 threads = 64 dims x 4 heads
    int i = t >> 2, h = t & 3;
    const float* w = We + ((size_t)i * 4 + h) * 128;
    const float* a = ae + (size_t)h * 128;
    float s = 0.f;
    for (int d = 0; d < 128; ++d) s += w[d] * a[d];
    v[i * 4 + h] = s;
}

// --------------------------------- fused GEMM: feat (bf16) + res (f32) + el/er
// A [M,128] bf16; Bt [(4D+D),128] bf16 (W^T rows 0..4D-1, res^T rows 4D..5D-1).
// cols < 4D -> featb bf16 + el/er partial dots (atomic); cols >= 4D -> y fp32.
template <int D>
__global__ __launch_bounds__(256) void gemm_fused(const short* __restrict__ A,
                                                  const short* __restrict__ Bt,
                                                  short* __restrict__ featb,
                                                  float* __restrict__ y,
                                                  float* __restrict__ el,
                                                  float* __restrict__ er,
                                                  const float* __restrict__ al,
                                                  const float* __restrict__ ar,
                                                  int M) {
    constexpr int HD = 4 * D;
    int wave = threadIdx.x >> 6, lane = threadIdx.x & 63;
    int m0 = blockIdx.y * 64;
    int n0 = blockIdx.x * 64 + wave * 16;
    int r = lane & 15, quad = lane >> 4;
    f32x4 acc[4] = {};
    const short* bp = Bt + (size_t)(n0 + r) * 128 + quad * 8;
    #pragma unroll
    for (int k0 = 0; k0 < 128; k0 += 32) {
        bf16x8 bfrag = *(const bf16x8*)(bp + k0);
        #pragma unroll
        for (int mt = 0; mt < 4; ++mt) {
            int gm = m0 + mt * 16 + r;
            bf16x8 afrag = {};
            if (gm < M) afrag = *(const bf16x8*)(A + (size_t)gm * 128 + k0 + quad * 8);
            acc[mt] = __builtin_amdgcn_mfma_f32_16x16x32_bf16(afrag, bfrag, acc[mt], 0, 0, 0);
        }
    }
    int col = n0 + r;
    if (col < HD) {
        int h = col / D;                 // wave-uniform (16-col tile within head)
        float alv = al[col];             // al flat [4*D]
        float arv = ar[col];
        #pragma unroll
        for (int mt = 0; mt < 4; ++mt) {
            #pragma unroll
            for (int rr = 0; rr < 4; ++rr) {
                int gm = m0 + mt * 16 + quad * 4 + rr;
                if (gm < M)
                    featb[(size_t)gm * HD + col] = f2b(acc[mt][rr]);
            }
            // partial el/er: reduce over the 16 cols (lanes r) of this wave-tile
            float ep[4], rp[4];
            #pragma unroll
            for (int rr = 0; rr < 4; ++rr) { ep[rr] = acc[mt][rr] * alv; rp[rr] = acc[mt][rr] * arv; }
            #pragma unroll
            for (int o = 1; o < 16; o <<= 1) {
                #pragma unroll
                for (int rr = 0; rr < 4; ++rr) {
                    ep[rr] += __shfl_xor(ep[rr], o);
                    rp[rr] += __shfl_xor(rp[rr], o);
                }
            }
            if (r == 0) {
                #pragma unroll
                for (int rr = 0; rr < 4; ++rr) {
                    int gm = m0 + mt * 16 + quad * 4 + rr;
                    if (gm < M) {
                        atomicAdd(&el[(size_t)gm * 4 + h], ep[rr]);
                        atomicAdd(&er[(size_t)gm * 4 + h], rp[rr]);
                    }
                }
            }
        }
    } else {
        int cl = col - HD;
        #pragma unroll
        for (int mt = 0; mt < 4; ++mt) {
            #pragma unroll
            for (int rr = 0; rr < 4; ++rr) {
                int gm = m0 + mt * 16 + quad * 4 + rr;
                if (gm < M) y[(size_t)gm * D + cl] = acc[mt][rr];
            }
        }
    }
}

// ----------------------- layer-1 edge-feature logit term, to sorted positions
__global__ __launch_bounds__(256) void edge_extra(const float* __restrict__ ef,
                                                  const float* __restrict__ vbuf,
                                                  const int* __restrict__ poe,
                                                  float* __restrict__ extra, int E) {
    __shared__ float vs[256];
    vs[threadIdx.x] = vbuf[threadIdx.x];
    __syncthreads();
    int e = blockIdx.x * 256 + threadIdx.x;
    if (e >= E) return;
    float a0 = 0.f, a1 = 0.f, a2 = 0.f, a3 = 0.f;
    const float4* e4 = (const float4*)(ef + (size_t)e * 64);
    #pragma unroll
    for (int c = 0; c < 16; ++c) {
        float4 x = e4[c];
        int b = c * 16;
        a0 += x.x * vs[b + 0] + x.y * vs[b + 4] + x.z * vs[b + 8] + x.w * vs[b + 12];
        a1 += x.x * vs[b + 1] + x.y * vs[b + 5] + x.z * vs[b + 9] + x.w * vs[b + 13];
        a2 += x.x * vs[b + 2] + x.y * vs[b + 6] + x.z * vs[b + 10] + x.w * vs[b + 14];
        a3 += x.x * vs[b + 3] + x.y * vs[b + 7] + x.z * vs[b + 11] + x.w * vs[b + 15];
    }
    float4 out; out.x = a0; out.y = a1; out.z = a2; out.w = a3;
    *(float4*)(extra + (size_t)poe[e] * 4) = out;
}

// ------- fused per-dst-node: logits -> leaky -> softmax -> aggregate -> epilogue
template <int D, bool HAS_EXTRA, bool WRITE_BF>
__global__ __launch_bounds__(256) void gat_node(const short* __restrict__ featb,
                                                const float* __restrict__ el,
                                                const float* __restrict__ er,
                                                const float* __restrict__ extra,
                                                const int* __restrict__ ssrc,
                                                const int* __restrict__ off,
                                                float* __restrict__ y,
                                                short* __restrict__ ybf) {
    constexpr int HD = 4 * D;
    constexpr int CH = HD / 512;   // 16B-chunks of a feat row per lane
    __shared__ float llog[4][MAXDEG];
    __shared__ float red[4][HD];
    __shared__ float scs[4];

    int n = blockIdx.x;
    int tid = threadIdx.x;
    int r0 = off[n];
    int deg = off[n + 1] - r0;
    if (deg > MAXDEG) deg = MAXDEG;   // (P(deg>256) ~ 0 for Binomial(160k,1e-4))

    // phase 1: logits + leaky relu into LDS
    float4 erv = *(const float4*)(er + (size_t)n * 4);
    for (int j = tid; j < deg; j += 256) {
        int s = ssrc[r0 + j];
        float4 elv = *(const float4*)(el + (size_t)s * 4);
        float a0 = elv.x + erv.x, a1 = elv.y + erv.y;
        float a2 = elv.z + erv.z, a3 = elv.w + erv.w;
        if (HAS_EXTRA) {
            float4 ex = *(const float4*)(extra + (size_t)(r0 + j) * 4);
            a0 += ex.x; a1 += ex.y; a2 += ex.z; a3 += ex.w;
        }
        llog[0][j] = a0 > 0.f ? a0 : 0.2f * a0;
        llog[1][j] = a1 > 0.f ? a1 : 0.2f * a1;
        llog[2][j] = a2 > 0.f ? a2 : 0.2f * a2;
        llog[3][j] = a3 > 0.f ? a3 : 0.2f * a3;
    }
    __syncthreads();

    // phase 2: per-head softmax (wave w handles head w)
    int wv = tid >> 6, ln = tid & 63;
    {
        float m = -1e30f;
        for (int j = ln; j < deg; j += 64) m = fmaxf(m, llog[wv][j]);
        #pragma unroll
        for (int o = 32; o; o >>= 1) m = fmaxf(m, __shfl_xor(m, o));
        float ssum = 0.f;
        for (int j = ln; j < deg; j += 64) {
            float ex = __expf(llog[wv][j] - m);
            llog[wv][j] = ex;
            ssum += ex;
        }
        #pragma unroll
        for (int o = 32; o; o >>= 1) ssum += __shfl_xor(ssum, o);
        if (ln == 0) scs[wv] = 0.25f / (ssum + 1e-9f);
    }
    __syncthreads();

    // phase 3: gather-aggregate; wave wv takes edges j = wv, wv+4, ...
    float acc[CH][8];
    #pragma unroll
    for (int c = 0; c < CH; ++c)
        #pragma unroll
        for (int i = 0; i < 8; ++i) acc[c][i] = 0.f;

    int hc[CH];
    #pragma unroll
    for (int c = 0; c < CH; ++c) hc[c] = (c * 512 + ln * 8) / D;

    int j = wv;
    for (; j + 4 < deg; j += 8) {
        int s0 = ssrc[r0 + j], s1 = ssrc[r0 + j + 4];
        const short* f0 = featb + (size_t)s0 * HD + ln * 8;
        const short* f1 = featb + (size_t)s1 * HD + ln * 8;
        uint4 v0[CH], v1[CH];
        #pragma unroll
        for (int c = 0; c < CH; ++c) {
            v0[c] = *(const uint4*)(f0 + c * 512);
            v1[c] = *(const uint4*)(f1 + c * 512);
        }
        #pragma unroll
        for (int c = 0; c < CH; ++c) {
            float w0 = llog[hc[c]][j], w1 = llog[hc[c]][j + 4];
            acc[c][0] += w0 * b2f((unsigned short)(v0[c].x & 0xFFFF)) + w1 * b2f((unsigned short)(v1[c].x & 0xFFFF));
            acc[c][1] += w0 * b2f((unsigned short)(v0[c].x >> 16))    + w1 * b2f((unsigned short)(v1[c].x >> 16));
            acc[c][2] += w0 * b2f((unsigned short)(v0[c].y & 0xFFFF)) + w1 * b2f((unsigned short)(v1[c].y & 0xFFFF));
            acc[c][3] += w0 * b2f((unsigned short)(v0[c].y >> 16))    + w1 * b2f((unsigned short)(v1[c].y >> 16));
            acc[c][4] += w0 * b2f((unsigned short)(v0[c].z & 0xFFFF)) + w1 * b2f((unsigned short)(v1[c].z & 0xFFFF));
            acc[c][5] += w0 * b2f((unsigned short)(v0[c].z >> 16))    + w1 * b2f((unsigned short)(v1[c].z >> 16));
            acc[c][6] += w0 * b2f((unsigned short)(v0[c].w & 0xFFFF)) + w1 * b2f((unsigned short)(v1[c].w & 0xFFFF));
            acc[c][7] += w0 * b2f((unsigned short)(v0[c].w >> 16))    + w1 * b2f((unsigned short)(v1[c].w >> 16));
        }
    }
    for (; j < deg; j += 4) {
        int s0 = ssrc[r0 + j];
        const short* f0 = featb + (size_t)s0 * HD + ln * 8;
        #pragma unroll
        for (int c = 0; c < CH; ++c) {
            uint4 v = *(const uint4*)(f0 + c * 512);
            float w = llog[hc[c]][j];
            acc[c][0] += w * b2f((unsigned short)(v.x & 0xFFFF));
            acc[c][1] += w * b2f((unsigned short)(v.x >> 16));
            acc[c][2] += w * b2f((unsigned short)(v.y & 0xFFFF));
            acc[c][3] += w * b2f((unsigned short)(v.y >> 16));
            acc[c][4] += w * b2f((unsigned short)(v.z & 0xFFFF));
            acc[c][5] += w * b2f((unsigned short)(v.z >> 16));
            acc[c][6] += w * b2f((unsigned short)(v.w & 0xFFFF));
            acc[c][7] += w * b2f((unsigned short)(v.w >> 16));
        }
    }
    #pragma unroll
    for (int c = 0; c < CH; ++c) {
        float sc = scs[hc[c]];
        #pragma unroll
        for (int i = 0; i < 8; ++i)
            red[wv][c * 512 + ln * 8 + i] = acc[c][i] * sc;
    }
    __syncthreads();

    // phase 4: head-mean + residual + relu (+ bf16 cast for next layer)
    for (int d = tid; d < D; d += 256) {
        float s = 0.f;
        #pragma unroll
        for (int w = 0; w < 4; ++w)
            #pragma unroll
            for (int h = 0; h < 4; ++h) s += red[w][h * D + d];
        float val = fmaxf(y[(size_t)n * D + d] + s, 0.f);
        y[(size_t)n * D + d] = val;
        if (WRITE_BF) ybf[(size_t)n * D + d] = f2b(val);
    }
}

// ---------------------------------------------------------------- host side
extern "C" void kernel_launch(void* const* d_in, const int* in_sizes, int n_in,
                              void* d_out, int out_size, void* d_ws, size_t ws_size,
                              hipStream_t stream) {
    const float* node_feats = (const float*)d_in[0];
    const float* edge_feats = (const float*)d_in[1];
    const int*   src        = (const int*)d_in[2];
    const int*   dst        = (const int*)d_in[3];
    const float* W1   = (const float*)d_in[4];
    const float* We1  = (const float*)d_in[5];
    const float* al1  = (const float*)d_in[6];
    const float* ar1  = (const float*)d_in[7];
    const float* ae1  = (const float*)d_in[8];
    const float* res1 = (const float*)d_in[9];
    const float* W2   = (const float*)d_in[10];
    const float* al2  = (const float*)d_in[11];
    const float* ar2  = (const float*)d_in[12];
    const float* res2 = (const float*)d_in[13];
    const float* W3   = (const float*)d_in[14];
    const float* al3  = (const float*)d_in[15];
    const float* ar3  = (const float*)d_in[16];
    const float* res3 = (const float*)d_in[17];
    const float* W4   = (const float*)d_in[18];
    const float* al4  = (const float*)d_in[19];
    const float* ar4  = (const float*)d_in[20];
    const float* res4 = (const float*)d_in[21];

    char* ws = (char*)d_ws;
    auto alloc = [&](size_t bytes) -> char* {
        char* p = ws;
        ws += (bytes + 255) & ~(size_t)255;
        return p;
    };
    int*   counts  = (int*)alloc((size_t)NN * 4);
    int*   offsets = (int*)alloc((size_t)(NN + 1) * 4);
    int*   cursor  = (int*)alloc((size_t)(NN + 1) * 4);
    int*   poe     = (int*)alloc((size_t)EE * 4);
    int*   ssrc    = (int*)alloc((size_t)EE * 4);
    short* featb   = (short*)alloc((size_t)NN * 1024 * 2);
    float* xA      = (float*)alloc((size_t)NN * 128 * 4);
    short* xb      = (short*)alloc((size_t)NN * 128 * 2);
    float* elr     = (float*)alloc((size_t)NN * 8 * 4);   // el | er
    float* extra   = (float*)alloc((size_t)EE * 4 * 4);
    float* vbuf    = (float*)alloc(1024);
    short* Wc1     = (short*)alloc((size_t)640 * 128 * 2);
    short* Wc2     = (short*)alloc((size_t)640 * 128 * 2);
    short* Wc3     = (short*)alloc((size_t)640 * 128 * 2);
    short* Wc4     = (short*)alloc((size_t)1280 * 128 * 2);
    float* el = elr;
    float* er = elr + (size_t)NN * 4;

    // CSR build (identical graph for all 4 layers)
    hipMemsetAsync(counts, 0, (size_t)NN * 4, stream);
    hist_kernel<<<(EE + 255) / 256, 256, 0, stream>>>(dst, counts, EE);
    scan_kernel<<<1, 256, 0, stream>>>(counts, offsets, cursor, NN);
    fill_kernel<<<(EE + 255) / 256, 256, 0, stream>>>(src, dst, cursor, ssrc, poe, EE);

    // layer-1 edge-term collapse
    compute_v<<<1, 256, 0, stream>>>(We1, ae1, vbuf);
    edge_extra<<<(EE + 255) / 256, 256, 0, stream>>>(edge_feats, vbuf, poe, extra, EE);

    // all weight transposes in one launch
    TParams P;
    P.src[0] = W1;   P.dst[0] = Wc1;              P.N[0] = 512;
    P.src[1] = W2;   P.dst[1] = Wc2;              P.N[1] = 512;
    P.src[2] = W3;   P.dst[2] = Wc3;              P.N[2] = 512;
    P.src[3] = W4;   P.dst[3] = Wc4;              P.N[3] = 1024;
    P.src[4] = res1; P.dst[4] = Wc1 + 512 * 128;  P.N[4] = 128;
    P.src[5] = res2; P.dst[5] = Wc2 + 512 * 128;  P.N[5] = 128;
    P.src[6] = res3; P.dst[6] = Wc3 + 512 * 128;  P.N[6] = 128;
    P.src[7] = res4; P.dst[7] = Wc4 + 1024 * 128; P.N[7] = 256;
    P.cum[0] = 0;
    for (int i = 0; i < 8; ++i) P.cum[i + 1] = P.cum[i] + P.N[i] * 128;
    transpose_all<<<(P.cum[8] + 255) / 256, 256, 0, stream>>>(P);

    cast_f2b_k<<<(NN * 128 + 255) / 256, 256, 0, stream>>>(node_feats, xb, NN * 128);

    float* out = (float*)d_out;
    dim3 g128(10, (NN + 63) / 64);   // (4*128+128)/64
    dim3 g256(20, (NN + 63) / 64);   // (4*256+256)/64

    // ---- layer 1
    hipMemsetAsync(elr, 0, (size_t)NN * 8 * 4, stream);
    gemm_fused<128><<<g128, 256, 0, stream>>>(xb, Wc1, featb, xA, el, er, al1, ar1, NN);
    gat_node<128, true, true><<<NN, 256, 0, stream>>>(featb, el, er, extra, ssrc, offsets, xA, xb);
    // ---- layer 2
    hipMemsetAsync(elr, 0, (size_t)NN * 8 * 4, stream);
    gemm_fused<128><<<g128, 256, 0, stream>>>(xb, Wc2, featb, xA, el, er, al2, ar2, NN);
    gat_node<128, false, true><<<NN, 256, 0, stream>>>(featb, el, er, nullptr, ssrc, offsets, xA, xb);
    // ---- layer 3
    hipMemsetAsync(elr, 0, (size_t)NN * 8 * 4, stream);
    gemm_fused<128><<<g128, 256, 0, stream>>>(xb, Wc3, featb, xA, el, er, al3, ar3, NN);
    gat_node<128, false, true><<<NN, 256, 0, stream>>>(featb, el, er, nullptr, ssrc, offsets, xA, xb);
    // ---- layer 4
    hipMemsetAsync(elr, 0, (size_t)NN * 8 * 4, stream);
    gemm_fused<256><<<g256, 256, 0, stream>>>(xb, Wc4, featb, out, el, er, al4, ar4, NN);
    gat_node<256, false, false><<<NN, 256, 0, stream>>>(featb, el, er, nullptr, ssrc, offsets, out, nullptr);
}

// Round 4
// 493.691 us; speedup vs baseline: 1.2595x; 1.2595x over previous
//
#include <hip/hip_runtime.h>

#define NN 10000
#define EE 160000
#define MAXDEG 256

typedef __attribute__((ext_vector_type(8))) short bf16x8;
typedef __attribute__((ext_vector_type(4))) float f32x4;

__device__ __forceinline__ float b2f(unsigned short s) {
    union { unsigned u; float f; } v; v.u = ((unsigned)s) << 16; return v.f;
}
__device__ __forceinline__ short f2b(float f) {
    union { float f; unsigned u; } v; v.f = f;
    unsigned r = v.u + 0x7FFF + ((v.u >> 16) & 1);  // RNE
    return (short)(r >> 16);
}

// ---------------------------------------------------------------- CSR build
__global__ __launch_bounds__(256) void hist_kernel(const int* __restrict__ dst,
                                                   int* __restrict__ counts, int E) {
    int e = blockIdx.x * 256 + threadIdx.x;
    if (e < E) atomicAdd(&counts[dst[e]], 1);
}

__global__ __launch_bounds__(256) void scan_kernel(const int* __restrict__ counts,
                                                   int* __restrict__ off,
                                                   int* __restrict__ cur, int n) {
    __shared__ int part[256];
    int tid = threadIdx.x;
    int chunk = (n + 255) / 256;
    int lo = tid * chunk; if (lo > n) lo = n;
    int hi = lo + chunk;  if (hi > n) hi = n;
    int s = 0;
    for (int i = lo; i < hi; ++i) s += counts[i];
    part[tid] = s;
    __syncthreads();
    for (int o = 1; o < 256; o <<= 1) {
        int v = (tid >= o) ? part[tid - o] : 0;
        __syncthreads();
        part[tid] += v;
        __syncthreads();
    }
    int run = (tid == 0) ? 0 : part[tid - 1];
    for (int i = lo; i < hi; ++i) { off[i] = run; cur[i] = run; run += counts[i]; }
    if (tid == 255) off[n] = part[255];
}

__global__ __launch_bounds__(256) void fill_kernel(const int* __restrict__ src,
                                                   const int* __restrict__ dst,
                                                   int* __restrict__ cur,
                                                   int* __restrict__ ssrc,
                                                   int* __restrict__ poe, int E) {
    int e = blockIdx.x * 256 + threadIdx.x;
    if (e < E) {
        int p = atomicAdd(&cur[dst[e]], 1);
        ssrc[p] = src[e];
        poe[e] = p;
    }
}

// ---------------------------------------------------------------- casts
__global__ __launch_bounds__(256) void cast_f2b_k(const float* __restrict__ x,
                                                  short* __restrict__ y, int n) {
    int t = blockIdx.x * 256 + threadIdx.x;
    if (t < n) y[t] = f2b(x[t]);
}

// all 8 weight transposes (K=128) in one launch
struct TParams {
    const float* src[8];
    short* dst[8];
    int N[8];
    int cum[9];
};
__global__ __launch_bounds__(256) void transpose_all(TParams P) {
    int t = blockIdx.x * 256 + threadIdx.x;
    if (t >= P.cum[8]) return;
    int i = 0;
    #pragma unroll
    for (int j = 1; j < 8; ++j) i += (t >= P.cum[j]);
    int local = t - P.cum[i];
    int n = local >> 7, k = local & 127;
    P.dst[i][local] = f2b(P.src[i][(size_t)k * P.N[i] + n]);
}

// ------------------------------------------------- v[i,h] = sum_d We[i,h,d]*ae[h,d]
__global__ void compute_v(const float* __restrict__ We, const float* __restrict__ ae,
                          float* __restrict__ v) {
    int t = threadIdx.x;        // 256 threads = 64 dims x 4 heads
    int i = t >> 2, h = t & 3;
    const float* w = We + ((size_t)i * 4 + h) * 128;
    const float* a = ae + (size_t)h * 128;
    float s = 0.f;
    for (int d = 0; d < 128; ++d) s += w[d] * a[d];
    v[i * 4 + h] = s;
}

// --------- wa rows: Bt[base+h][k]   = sum_d W[k,h,d]*al[h,d]   (el columns)
//                    Bt[base+4+h][k] = sum_d W[k,h,d]*ar[h,d]   (er columns)
template <int D>
__global__ __launch_bounds__(256) void compute_wa(const float* __restrict__ W,
                                                  const float* __restrict__ al,
                                                  const float* __restrict__ ar,
                                                  short* __restrict__ Bt, int base) {
    int t = blockIdx.x * 256 + threadIdx.x;
    if (t >= 512) return;
    int k = t >> 2, h = t & 3;
    const float* w = W + ((size_t)k * 4 + h) * D;
    const float* a = al + (size_t)h * D;
    const float* r = ar + (size_t)h * D;
    float sa = 0.f, sr = 0.f;
    for (int d = 0; d < D; ++d) { sa += w[d] * a[d]; sr += w[d] * r[d]; }
    Bt[(size_t)(base + h) * 128 + k]     = f2b(sa);
    Bt[(size_t)(base + 4 + h) * 128 + k] = f2b(sr);
}

// --------------------------------- fused GEMM: feat (bf16) + res (f32) + el/er
// A [M,128] bf16; Bt [(4D+D+8+pad),128] bf16:
//   rows 0..4D-1 = W^T; 4D..5D-1 = res^T; 5D..5D+7 = wa/war; rest zero pad.
// cols < 4D -> featb bf16; < 5D -> y fp32; < 5D+8 -> elr [M][8] fp32.
template <int D>
__global__ __launch_bounds__(256) void gemm_fused(const short* __restrict__ A,
                                                  const short* __restrict__ Bt,
                                                  short* __restrict__ featb,
                                                  float* __restrict__ y,
                                                  float* __restrict__ elr,
                                                  int M) {
    constexpr int HD = 4 * D;
    int wave = threadIdx.x >> 6, lane = threadIdx.x & 63;
    int m0 = blockIdx.y * 64;
    int n0 = blockIdx.x * 64 + wave * 16;
    int r = lane & 15, quad = lane >> 4;
    f32x4 acc[4] = {};
    const short* bp = Bt + (size_t)(n0 + r) * 128 + quad * 8;
    #pragma unroll
    for (int k0 = 0; k0 < 128; k0 += 32) {
        bf16x8 bfrag = *(const bf16x8*)(bp + k0);
        #pragma unroll
        for (int mt = 0; mt < 4; ++mt) {
            int gm = m0 + mt * 16 + r;
            bf16x8 afrag = {};
            if (gm < M) afrag = *(const bf16x8*)(A + (size_t)gm * 128 + k0 + quad * 8);
            acc[mt] = __builtin_amdgcn_mfma_f32_16x16x32_bf16(afrag, bfrag, acc[mt], 0, 0, 0);
        }
    }
    int col = n0 + r;
    #pragma unroll
    for (int mt = 0; mt < 4; ++mt) {
        #pragma unroll
        for (int rr = 0; rr < 4; ++rr) {
            int gm = m0 + mt * 16 + quad * 4 + rr;
            if (gm >= M) continue;
            float v = acc[mt][rr];
            if (col < HD)             featb[(size_t)gm * HD + col] = f2b(v);
            else if (col < HD + D)    y[(size_t)gm * D + (col - HD)] = v;
            else if (col < HD + D + 8) elr[(size_t)gm * 8 + (col - HD - D)] = v;
        }
    }
}

// ----------------------- layer-1 edge-feature logit term, to sorted positions
__global__ __launch_bounds__(256) void edge_extra(const float* __restrict__ ef,
                                                  const float* __restrict__ vbuf,
                                                  const int* __restrict__ poe,
                                                  float* __restrict__ extra, int E) {
    __shared__ float vs[256];
    vs[threadIdx.x] = vbuf[threadIdx.x];
    __syncthreads();
    int e = blockIdx.x * 256 + threadIdx.x;
    if (e >= E) return;
    float a0 = 0.f, a1 = 0.f, a2 = 0.f, a3 = 0.f;
    const float4* e4 = (const float4*)(ef + (size_t)e * 64);
    #pragma unroll
    for (int c = 0; c < 16; ++c) {
        float4 x = e4[c];
        int b = c * 16;
        a0 += x.x * vs[b + 0] + x.y * vs[b + 4] + x.z * vs[b + 8] + x.w * vs[b + 12];
        a1 += x.x * vs[b + 1] + x.y * vs[b + 5] + x.z * vs[b + 9] + x.w * vs[b + 13];
        a2 += x.x * vs[b + 2] + x.y * vs[b + 6] + x.z * vs[b + 10] + x.w * vs[b + 14];
        a3 += x.x * vs[b + 3] + x.y * vs[b + 7] + x.z * vs[b + 11] + x.w * vs[b + 15];
    }
    float4 out; out.x = a0; out.y = a1; out.z = a2; out.w = a3;
    *(float4*)(extra + (size_t)poe[e] * 4) = out;
}

// ------- fused per-dst-node: logits -> leaky -> softmax -> aggregate -> epilogue
template <int D, bool HAS_EXTRA, bool WRITE_BF>
__global__ __launch_bounds__(256) void gat_node(const short* __restrict__ featb,
                                                const float* __restrict__ elr,
                                                const float* __restrict__ extra,
                                                const int* __restrict__ ssrc,
                                                const int* __restrict__ off,
                                                float* __restrict__ y,
                                                short* __restrict__ ybf) {
    constexpr int HD = 4 * D;
    constexpr int CH = HD / 512;   // 16B-chunks of a feat row per lane
    __shared__ float llog[4][MAXDEG];
    __shared__ float red[4][HD];
    __shared__ float scs[4];

    int n = blockIdx.x;
    int tid = threadIdx.x;
    int r0 = off[n];
    int deg = off[n + 1] - r0;
    if (deg > MAXDEG) deg = MAXDEG;

    // phase 1: logits + leaky relu into LDS
    float4 erv = *(const float4*)(elr + (size_t)n * 8 + 4);
    for (int j = tid; j < deg; j += 256) {
        int s = ssrc[r0 + j];
        float4 elv = *(const float4*)(elr + (size_t)s * 8);
        float a0 = elv.x + erv.x, a1 = elv.y + erv.y;
        float a2 = elv.z + erv.z, a3 = elv.w + erv.w;
        if (HAS_EXTRA) {
            float4 ex = *(const float4*)(extra + (size_t)(r0 + j) * 4);
            a0 += ex.x; a1 += ex.y; a2 += ex.z; a3 += ex.w;
        }
        llog[0][j] = a0 > 0.f ? a0 : 0.2f * a0;
        llog[1][j] = a1 > 0.f ? a1 : 0.2f * a1;
        llog[2][j] = a2 > 0.f ? a2 : 0.2f * a2;
        llog[3][j] = a3 > 0.f ? a3 : 0.2f * a3;
    }
    __syncthreads();

    // phase 2: per-head softmax (wave w handles head w)
    int wv = tid >> 6, ln = tid & 63;
    {
        float m = -1e30f;
        for (int j = ln; j < deg; j += 64) m = fmaxf(m, llog[wv][j]);
        #pragma unroll
        for (int o = 32; o; o >>= 1) m = fmaxf(m, __shfl_xor(m, o));
        float ssum = 0.f;
        for (int j = ln; j < deg; j += 64) {
            float ex = __expf(llog[wv][j] - m);
            llog[wv][j] = ex;
            ssum += ex;
        }
        #pragma unroll
        for (int o = 32; o; o >>= 1) ssum += __shfl_xor(ssum, o);
        if (ln == 0) scs[wv] = 0.25f / (ssum + 1e-9f);
    }
    __syncthreads();

    // phase 3: gather-aggregate; wave wv takes edges j = wv, wv+4, ...
    float acc[CH][8];
    #pragma unroll
    for (int c = 0; c < CH; ++c)
        #pragma unroll
        for (int i = 0; i < 8; ++i) acc[c][i] = 0.f;

    int hc[CH];
    #pragma unroll
    for (int c = 0; c < CH; ++c) hc[c] = (c * 512 + ln * 8) / D;

    int j = wv;
    for (; j + 4 < deg; j += 8) {
        int s0 = ssrc[r0 + j], s1 = ssrc[r0 + j + 4];
        const short* f0 = featb + (size_t)s0 * HD + ln * 8;
        const short* f1 = featb + (size_t)s1 * HD + ln * 8;
        uint4 v0[CH], v1[CH];
        #pragma unroll
        for (int c = 0; c < CH; ++c) {
            v0[c] = *(const uint4*)(f0 + c * 512);
            v1[c] = *(const uint4*)(f1 + c * 512);
        }
        #pragma unroll
        for (int c = 0; c < CH; ++c) {
            float w0 = llog[hc[c]][j], w1 = llog[hc[c]][j + 4];
            acc[c][0] += w0 * b2f((unsigned short)(v0[c].x & 0xFFFF)) + w1 * b2f((unsigned short)(v1[c].x & 0xFFFF));
            acc[c][1] += w0 * b2f((unsigned short)(v0[c].x >> 16))    + w1 * b2f((unsigned short)(v1[c].x >> 16));
            acc[c][2] += w0 * b2f((unsigned short)(v0[c].y & 0xFFFF)) + w1 * b2f((unsigned short)(v1[c].y & 0xFFFF));
            acc[c][3] += w0 * b2f((unsigned short)(v0[c].y >> 16))    + w1 * b2f((unsigned short)(v1[c].y >> 16));
            acc[c][4] += w0 * b2f((unsigned short)(v0[c].z & 0xFFFF)) + w1 * b2f((unsigned short)(v1[c].z & 0xFFFF));
            acc[c][5] += w0 * b2f((unsigned short)(v0[c].z >> 16))    + w1 * b2f((unsigned short)(v1[c].z >> 16));
            acc[c][6] += w0 * b2f((unsigned short)(v0[c].w & 0xFFFF)) + w1 * b2f((unsigned short)(v1[c].w & 0xFFFF));
            acc[c][7] += w0 * b2f((unsigned short)(v0[c].w >> 16))    + w1 * b2f((unsigned short)(v1[c].w >> 16));
        }
    }
    for (; j < deg; j += 4) {
        int s0 = ssrc[r0 + j];
        const short* f0 = featb + (size_t)s0 * HD + ln * 8;
        #pragma unroll
        for (int c = 0; c < CH; ++c) {
            uint4 v = *(const uint4*)(f0 + c * 512);
            float w = llog[hc[c]][j];
            acc[c][0] += w * b2f((unsigned short)(v.x & 0xFFFF));
            acc[c][1] += w * b2f((unsigned short)(v.x >> 16));
            acc[c][2] += w * b2f((unsigned short)(v.y & 0xFFFF));
            acc[c][3] += w * b2f((unsigned short)(v.y >> 16));
            acc[c][4] += w * b2f((unsigned short)(v.z & 0xFFFF));
            acc[c][5] += w * b2f((unsigned short)(v.z >> 16));
            acc[c][6] += w * b2f((unsigned short)(v.w & 0xFFFF));
            acc[c][7] += w * b2f((unsigned short)(v.w >> 16));
        }
    }
    #pragma unroll
    for (int c = 0; c < CH; ++c) {
        float sc = scs[hc[c]];
        #pragma unroll
        for (int i = 0; i < 8; ++i)
            red[wv][c * 512 + ln * 8 + i] = acc[c][i] * sc;
    }
    __syncthreads();

    // phase 4: head-mean + residual + relu (+ bf16 cast for next layer)
    for (int d = tid; d < D; d += 256) {
        float s = 0.f;
        #pragma unroll
        for (int w = 0; w < 4; ++w)
            #pragma unroll
            for (int h = 0; h < 4; ++h) s += red[w][h * D + d];
        float val = fmaxf(y[(size_t)n * D + d] + s, 0.f);
        y[(size_t)n * D + d] = val;
        if (WRITE_BF) ybf[(size_t)n * D + d] = f2b(val);
    }
}

// ---------------------------------------------------------------- host side
extern "C" void kernel_launch(void* const* d_in, const int* in_sizes, int n_in,
                              void* d_out, int out_size, void* d_ws, size_t ws_size,
                              hipStream_t stream) {
    const float* node_feats = (const float*)d_in[0];
    const float* edge_feats = (const float*)d_in[1];
    const int*   src        = (const int*)d_in[2];
    const int*   dst        = (const int*)d_in[3];
    const float* W1   = (const float*)d_in[4];
    const float* We1  = (const float*)d_in[5];
    const float* al1  = (const float*)d_in[6];
    const float* ar1  = (const float*)d_in[7];
    const float* ae1  = (const float*)d_in[8];
    const float* res1 = (const float*)d_in[9];
    const float* W2   = (const float*)d_in[10];
    const float* al2  = (const float*)d_in[11];
    const float* ar2  = (const float*)d_in[12];
    const float* res2 = (const float*)d_in[13];
    const float* W3   = (const float*)d_in[14];
    const float* al3  = (const float*)d_in[15];
    const float* ar3  = (const float*)d_in[16];
    const float* res3 = (const float*)d_in[17];
    const float* W4   = (const float*)d_in[18];
    const float* al4  = (const float*)d_in[19];
    const float* ar4  = (const float*)d_in[20];
    const float* res4 = (const float*)d_in[21];

    char* ws = (char*)d_ws;
    auto alloc = [&](size_t bytes) -> char* {
        char* p = ws;
        ws += (bytes + 255) & ~(size_t)255;
        return p;
    };
    int*   counts  = (int*)alloc((size_t)NN * 4);
    int*   offsets = (int*)alloc((size_t)(NN + 1) * 4);
    int*   cursor  = (int*)alloc((size_t)(NN + 1) * 4);
    int*   poe     = (int*)alloc((size_t)EE * 4);
    int*   ssrc    = (int*)alloc((size_t)EE * 4);
    short* featb   = (short*)alloc((size_t)NN * 1024 * 2);
    float* xA      = (float*)alloc((size_t)NN * 128 * 4);
    short* xb      = (short*)alloc((size_t)NN * 128 * 2);
    float* elr     = (float*)alloc((size_t)NN * 8 * 4);   // [n][0..3]=el, [4..7]=er
    float* extra   = (float*)alloc((size_t)EE * 4 * 4);
    float* vbuf    = (float*)alloc(1024);
    short* Wc1     = (short*)alloc((size_t)704 * 128 * 2);
    short* Wc2     = (short*)alloc((size_t)704 * 128 * 2);
    short* Wc3     = (short*)alloc((size_t)704 * 128 * 2);
    short* Wc4     = (short*)alloc((size_t)1344 * 128 * 2);

    // CSR build (identical graph for all 4 layers)
    hipMemsetAsync(counts, 0, (size_t)NN * 4, stream);
    hist_kernel<<<(EE + 255) / 256, 256, 0, stream>>>(dst, counts, EE);
    scan_kernel<<<1, 256, 0, stream>>>(counts, offsets, cursor, NN);
    fill_kernel<<<(EE + 255) / 256, 256, 0, stream>>>(src, dst, cursor, ssrc, poe, EE);

    // layer-1 edge-term collapse
    compute_v<<<1, 256, 0, stream>>>(We1, ae1, vbuf);
    edge_extra<<<(EE + 255) / 256, 256, 0, stream>>>(edge_feats, vbuf, poe, extra, EE);

    // zero the pad rows of each fused-weight matrix (ws is poisoned 0xAA)
    hipMemsetAsync(Wc1 + (size_t)648 * 128, 0, (size_t)(704 - 648) * 128 * 2, stream);
    hipMemsetAsync(Wc2 + (size_t)648 * 128, 0, (size_t)(704 - 648) * 128 * 2, stream);
    hipMemsetAsync(Wc3 + (size_t)648 * 128, 0, (size_t)(704 - 648) * 128 * 2, stream);
    hipMemsetAsync(Wc4 + (size_t)1288 * 128, 0, (size_t)(1344 - 1288) * 128 * 2, stream);

    // all weight transposes in one launch
    TParams P;
    P.src[0] = W1;   P.dst[0] = Wc1;              P.N[0] = 512;
    P.src[1] = W2;   P.dst[1] = Wc2;              P.N[1] = 512;
    P.src[2] = W3;   P.dst[2] = Wc3;              P.N[2] = 512;
    P.src[3] = W4;   P.dst[3] = Wc4;              P.N[3] = 1024;
    P.src[4] = res1; P.dst[4] = Wc1 + 512 * 128;  P.N[4] = 128;
    P.src[5] = res2; P.dst[5] = Wc2 + 512 * 128;  P.N[5] = 128;
    P.src[6] = res3; P.dst[6] = Wc3 + 512 * 128;  P.N[6] = 128;
    P.src[7] = res4; P.dst[7] = Wc4 + 1024 * 128; P.N[7] = 256;
    P.cum[0] = 0;
    for (int i = 0; i < 8; ++i) P.cum[i + 1] = P.cum[i] + P.N[i] * 128;
    transpose_all<<<(P.cum[8] + 255) / 256, 256, 0, stream>>>(P);

    // collapsed el/er weight columns
    compute_wa<128><<<2, 256, 0, stream>>>(W1, al1, ar1, Wc1, 640);
    compute_wa<128><<<2, 256, 0, stream>>>(W2, al2, ar2, Wc2, 640);
    compute_wa<128><<<2, 256, 0, stream>>>(W3, al3, ar3, Wc3, 640);
    compute_wa<256><<<2, 256, 0, stream>>>(W4, al4, ar4, Wc4, 1280);

    cast_f2b_k<<<(NN * 128 + 255) / 256, 256, 0, stream>>>(node_feats, xb, NN * 128);

    float* out = (float*)d_out;
    dim3 g128(11, (NN + 63) / 64);   // 704/64
    dim3 g256(21, (NN + 63) / 64);   // 1344/64

    // ---- layer 1
    gemm_fused<128><<<g128, 256, 0, stream>>>(xb, Wc1, featb, xA, elr, NN);
    gat_node<128, true, true><<<NN, 256, 0, stream>>>(featb, elr, extra, ssrc, offsets, xA, xb);
    // ---- layer 2
    gemm_fused<128><<<g128, 256, 0, stream>>>(xb, Wc2, featb, xA, elr, NN);
    gat_node<128, false, true><<<NN, 256, 0, stream>>>(featb, elr, nullptr, ssrc, offsets, xA, xb);
    // ---- layer 3
    gemm_fused<128><<<g128, 256, 0, stream>>>(xb, Wc3, featb, xA, elr, NN);
    gat_node<128, false, true><<<NN, 256, 0, stream>>>(featb, elr, nullptr, ssrc, offsets, xA, xb);
    // ---- layer 4
    gemm_fused<256><<<g256, 256, 0, stream>>>(xb, Wc4, featb, out, elr, NN);
    gat_node<256, false, false><<<NN, 256, 0, stream>>>(featb, elr, nullptr, ssrc, offsets, out, nullptr);
}

// Round 5
// 438.060 us; speedup vs baseline: 1.4194x; 1.1270x over previous
//
#include <hip/hip_runtime.h>

#define NN 10000
#define EE 160000

typedef __attribute__((ext_vector_type(8))) short bf16x8;
typedef __attribute__((ext_vector_type(4))) float f32x4;

__device__ __forceinline__ float b2f(unsigned short s) {
    union { unsigned u; float f; } v; v.u = ((unsigned)s) << 16; return v.f;
}
__device__ __forceinline__ short f2b(float f) {
    union { float f; unsigned u; } v; v.f = f;
    unsigned r = v.u + 0x7FFF + ((v.u >> 16) & 1);  // RNE
    return (short)(r >> 16);
}

// ---------------------------------------------------------------- CSR build
__global__ __launch_bounds__(256) void hist_kernel(const int* __restrict__ dst,
                                                   int* __restrict__ counts, int E) {
    int e = blockIdx.x * 256 + threadIdx.x;
    if (e < E) atomicAdd(&counts[dst[e]], 1);
}

__global__ __launch_bounds__(256) void scan_kernel(const int* __restrict__ counts,
                                                   int* __restrict__ off,
                                                   int* __restrict__ cur, int n) {
    __shared__ int part[256];
    int tid = threadIdx.x;
    int chunk = (n + 255) / 256;
    int lo = tid * chunk; if (lo > n) lo = n;
    int hi = lo + chunk;  if (hi > n) hi = n;
    int s = 0;
    for (int i = lo; i < hi; ++i) s += counts[i];
    part[tid] = s;
    __syncthreads();
    for (int o = 1; o < 256; o <<= 1) {
        int v = (tid >= o) ? part[tid - o] : 0;
        __syncthreads();
        part[tid] += v;
        __syncthreads();
    }
    int run = (tid == 0) ? 0 : part[tid - 1];
    for (int i = lo; i < hi; ++i) { off[i] = run; cur[i] = run; run += counts[i]; }
    if (tid == 255) off[n] = part[255];
}

// fill + layer-1 edge-extra fused: writes ssrc[p] and extra[p] directly
__global__ __launch_bounds__(256) void fill_extra(const int* __restrict__ src,
                                                  const int* __restrict__ dst,
                                                  int* __restrict__ cur,
                                                  const float* __restrict__ ef,
                                                  const float* __restrict__ vbuf,
                                                  int* __restrict__ ssrc,
                                                  float* __restrict__ extra, int E) {
    __shared__ float vs[256];
    vs[threadIdx.x] = vbuf[threadIdx.x];
    __syncthreads();
    int e = blockIdx.x * 256 + threadIdx.x;
    if (e >= E) return;
    int p = atomicAdd(&cur[dst[e]], 1);
    ssrc[p] = src[e];
    float a0 = 0.f, a1 = 0.f, a2 = 0.f, a3 = 0.f;
    const float4* e4 = (const float4*)(ef + (size_t)e * 64);
    #pragma unroll
    for (int c = 0; c < 16; ++c) {
        float4 x = e4[c];
        int b = c * 16;
        a0 += x.x * vs[b + 0] + x.y * vs[b + 4] + x.z * vs[b + 8] + x.w * vs[b + 12];
        a1 += x.x * vs[b + 1] + x.y * vs[b + 5] + x.z * vs[b + 9] + x.w * vs[b + 13];
        a2 += x.x * vs[b + 2] + x.y * vs[b + 6] + x.z * vs[b + 10] + x.w * vs[b + 14];
        a3 += x.x * vs[b + 3] + x.y * vs[b + 7] + x.z * vs[b + 11] + x.w * vs[b + 15];
    }
    float4 o; o.x = a0; o.y = a1; o.z = a2; o.w = a3;
    *(float4*)(extra + (size_t)p * 4) = o;
}

// --------------------------- one prep kernel: transposes, wa, v, cast, zero
struct PrepParams {
    const float* tsrc[8];
    short* tdst[8];
    int tN[8];
    int tcum[9];
    const float* W[4]; const float* al[4]; const float* ar[4];
    short* Wc[4]; int Dl[4]; int base[4];
    const float* We1; const float* ae1; float* vbuf;
    const float* node_feats; short* xb;
    int* counts;
    int bT, bV, bWA, bC, bZ;   // block-range starts
};
__global__ __launch_bounds__(256) void prep_kernel(PrepParams P) {
    int blk = blockIdx.x, tid = threadIdx.x;
    if (blk < P.bV) {                       // transposes: W[128,N]f32 -> Wt[N,128]bf16
        int t = blk * 256 + tid;
        if (t >= P.tcum[8]) return;
        int i = 0;
        #pragma unroll
        for (int j = 1; j < 8; ++j) i += (t >= P.tcum[j]);
        int local = t - P.tcum[i];
        int n = local >> 7, k = local & 127;
        P.tdst[i][local] = f2b(P.tsrc[i][(size_t)k * P.tN[i] + n]);
    } else if (blk < P.bWA) {               // compute_v: v[i,h]=sum_d We[i,h,d]*ae[h,d]
        int i = tid >> 2, h = tid & 3;
        const float* w = P.We1 + ((size_t)i * 4 + h) * 128;
        const float* a = P.ae1 + (size_t)h * 128;
        float s = 0.f;
        for (int d = 0; d < 128; ++d) s += w[d] * a[d];
        P.vbuf[i * 4 + h] = s;
    } else if (blk < P.bC) {                // wa columns for el/er
        int j = blk - P.bWA;                // 0..7
        int l = j >> 1, half = j & 1;
        int tt = half * 256 + tid;          // 0..511
        int k = tt >> 2, h = tt & 3;
        int D = P.Dl[l];
        const float* w = P.W[l] + ((size_t)k * 4 + h) * D;
        const float* a = P.al[l] + (size_t)h * D;
        const float* r = P.ar[l] + (size_t)h * D;
        float sa = 0.f, sr = 0.f;
        for (int d = 0; d < D; ++d) { sa += w[d] * a[d]; sr += w[d] * r[d]; }
        P.Wc[l][(size_t)(P.base[l] + h) * 128 + k]     = f2b(sa);
        P.Wc[l][(size_t)(P.base[l] + 4 + h) * 128 + k] = f2b(sr);
    } else if (blk < P.bZ) {                // cast node_feats -> bf16
        int t = (blk - P.bC) * 256 + tid;
        if (t < NN * 128) P.xb[t] = f2b(P.node_feats[t]);
    } else {                                // zero counts
        int t = (blk - P.bZ) * 256 + tid;
        if (t < NN) P.counts[t] = 0;
    }
}

// --------------------------------- fused GEMM: feat (bf16) + res (f32) + el/er
template <int D>
__global__ __launch_bounds__(256) void gemm_fused(const short* __restrict__ A,
                                                  const short* __restrict__ Bt,
                                                  short* __restrict__ featb,
                                                  float* __restrict__ y,
                                                  float* __restrict__ elr,
                                                  int M) {
    constexpr int HD = 4 * D;
    int wave = threadIdx.x >> 6, lane = threadIdx.x & 63;
    int m0 = blockIdx.y * 64;
    int n0 = blockIdx.x * 64 + wave * 16;
    int r = lane & 15, quad = lane >> 4;
    f32x4 acc[4] = {};
    const short* bp = Bt + (size_t)(n0 + r) * 128 + quad * 8;
    #pragma unroll
    for (int k0 = 0; k0 < 128; k0 += 32) {
        bf16x8 bfrag = *(const bf16x8*)(bp + k0);
        #pragma unroll
        for (int mt = 0; mt < 4; ++mt) {
            int gm = m0 + mt * 16 + r;
            bf16x8 afrag = {};
            if (gm < M) afrag = *(const bf16x8*)(A + (size_t)gm * 128 + k0 + quad * 8);
            acc[mt] = __builtin_amdgcn_mfma_f32_16x16x32_bf16(afrag, bfrag, acc[mt], 0, 0, 0);
        }
    }
    int col = n0 + r;
    #pragma unroll
    for (int mt = 0; mt < 4; ++mt) {
        #pragma unroll
        for (int rr = 0; rr < 4; ++rr) {
            int gm = m0 + mt * 16 + quad * 4 + rr;
            if (gm >= M) continue;
            float v = acc[mt][rr];
            if (col < HD)              featb[(size_t)gm * HD + col] = f2b(v);
            else if (col < HD + D)     y[(size_t)gm * D + (col - HD)] = v;
            else if (col < HD + D + 8) elr[(size_t)gm * 8 + (col - HD - D)] = v;
        }
    }
}

// ------------------------------------------------- wave-per-node fused GAT
__device__ __forceinline__ void accum8(float* a, uint4 v, float w) {
    a[0] += w * b2f((unsigned short)(v.x & 0xFFFF));
    a[1] += w * b2f((unsigned short)(v.x >> 16));
    a[2] += w * b2f((unsigned short)(v.y & 0xFFFF));
    a[3] += w * b2f((unsigned short)(v.y >> 16));
    a[4] += w * b2f((unsigned short)(v.z & 0xFFFF));
    a[5] += w * b2f((unsigned short)(v.z >> 16));
    a[6] += w * b2f((unsigned short)(v.w & 0xFFFF));
    a[7] += w * b2f((unsigned short)(v.w >> 16));
}

template <int CH>
__device__ __forceinline__ void gather_chunk(int cnt, int sidx,
                                             float e0, float e1, float e2, float e3,
                                             const short* __restrict__ featb, int ln,
                                             float acc[CH][8]) {
    constexpr int HD = CH * 512;
    const short* base = featb + ln * 8;
    int j = 0;
    for (; j + 2 <= cnt; j += 2) {
        int sA = __shfl(sidx, j), sB = __shfl(sidx, j + 1);
        float wA0 = __shfl(e0, j), wA1 = __shfl(e1, j), wA2 = __shfl(e2, j), wA3 = __shfl(e3, j);
        float wB0 = __shfl(e0, j + 1), wB1 = __shfl(e1, j + 1), wB2 = __shfl(e2, j + 1), wB3 = __shfl(e3, j + 1);
        const short* fA = base + (size_t)sA * HD;
        const short* fB = base + (size_t)sB * HD;
        uint4 vA[CH], vB[CH];
        #pragma unroll
        for (int c = 0; c < CH; ++c) { vA[c] = *(const uint4*)(fA + c * 512); vB[c] = *(const uint4*)(fB + c * 512); }
        #pragma unroll
        for (int c = 0; c < CH; ++c) {
            float wA, wB;
            if (CH == 1) {
                wA = ln < 16 ? wA0 : ln < 32 ? wA1 : ln < 48 ? wA2 : wA3;
                wB = ln < 16 ? wB0 : ln < 32 ? wB1 : ln < 48 ? wB2 : wB3;
            } else {
                wA = (c == 0) ? (ln < 32 ? wA0 : wA1) : (ln < 32 ? wA2 : wA3);
                wB = (c == 0) ? (ln < 32 ? wB0 : wB1) : (ln < 32 ? wB2 : wB3);
            }
            accum8(acc[c], vA[c], wA);
            accum8(acc[c], vB[c], wB);
        }
    }
    if (j < cnt) {
        int sA = __shfl(sidx, j);
        float wA0 = __shfl(e0, j), wA1 = __shfl(e1, j), wA2 = __shfl(e2, j), wA3 = __shfl(e3, j);
        const short* fA = base + (size_t)sA * HD;
        #pragma unroll
        for (int c = 0; c < CH; ++c) {
            uint4 vA = *(const uint4*)(fA + c * 512);
            float wA;
            if (CH == 1) wA = ln < 16 ? wA0 : ln < 32 ? wA1 : ln < 48 ? wA2 : wA3;
            else         wA = (c == 0) ? (ln < 32 ? wA0 : wA1) : (ln < 32 ? wA2 : wA3);
            accum8(acc[c], vA, wA);
        }
    }
}

template <int D, bool HAS_EXTRA, bool WRITE_BF>
__global__ __launch_bounds__(256) void gat_wave(const short* __restrict__ featb,
                                                const float* __restrict__ elr,
                                                const float* __restrict__ extra,
                                                const int* __restrict__ ssrc,
                                                const int* __restrict__ off,
                                                const float* __restrict__ yres,
                                                float* __restrict__ yout,
                                                short* __restrict__ ybf) {
    constexpr int HD = 4 * D;
    constexpr int CH = HD / 512;
    int wv = threadIdx.x >> 6, ln = threadIdx.x & 63;
    int n = blockIdx.x * 4 + wv;        // NN % 4 == 0
    int r0 = off[n], deg = off[n + 1] - r0;

    float4 erv = *(const float4*)(elr + (size_t)n * 8 + 4);

    float acc[CH][8];
    #pragma unroll
    for (int c = 0; c < CH; ++c)
        #pragma unroll
        for (int i = 0; i < 8; ++i) acc[c][i] = 0.f;

    float sc0, sc1, sc2, sc3;

    auto logits = [&](int idx, float& a0, float& a1, float& a2, float& a3) {
        int s = ssrc[idx];
        float4 elv = *(const float4*)(elr + (size_t)s * 8);
        a0 = elv.x + erv.x; a1 = elv.y + erv.y; a2 = elv.z + erv.z; a3 = elv.w + erv.w;
        if (HAS_EXTRA) {
            float4 exv = *(const float4*)(extra + (size_t)idx * 4);
            a0 += exv.x; a1 += exv.y; a2 += exv.z; a3 += exv.w;
        }
        a0 = a0 > 0.f ? a0 : 0.2f * a0;
        a1 = a1 > 0.f ? a1 : 0.2f * a1;
        a2 = a2 > 0.f ? a2 : 0.2f * a2;
        a3 = a3 > 0.f ? a3 : 0.2f * a3;
        return s;
    };

    if (deg <= 64) {
        int sidx = 0;
        float a0 = -1e30f, a1 = -1e30f, a2 = -1e30f, a3 = -1e30f;
        if (ln < deg) sidx = logits(r0 + ln, a0, a1, a2, a3);
        float m0 = a0, m1 = a1, m2 = a2, m3 = a3;
        #pragma unroll
        for (int o = 32; o; o >>= 1) {
            m0 = fmaxf(m0, __shfl_xor(m0, o)); m1 = fmaxf(m1, __shfl_xor(m1, o));
            m2 = fmaxf(m2, __shfl_xor(m2, o)); m3 = fmaxf(m3, __shfl_xor(m3, o));
        }
        float e0 = 0.f, e1 = 0.f, e2 = 0.f, e3 = 0.f;
        if (ln < deg) {
            e0 = __expf(a0 - m0); e1 = __expf(a1 - m1);
            e2 = __expf(a2 - m2); e3 = __expf(a3 - m3);
        }
        float s0 = e0, s1 = e1, s2 = e2, s3 = e3;
        #pragma unroll
        for (int o = 32; o; o >>= 1) {
            s0 += __shfl_xor(s0, o); s1 += __shfl_xor(s1, o);
            s2 += __shfl_xor(s2, o); s3 += __shfl_xor(s3, o);
        }
        sc0 = 0.25f / (s0 + 1e-9f); sc1 = 0.25f / (s1 + 1e-9f);
        sc2 = 0.25f / (s2 + 1e-9f); sc3 = 0.25f / (s3 + 1e-9f);
        gather_chunk<CH>(deg, sidx, e0, e1, e2, e3, featb, ln, acc);
    } else {
        // never expected (P(deg>64) ~ 0), kept for correctness
        float m0 = -1e30f, m1 = -1e30f, m2 = -1e30f, m3 = -1e30f;
        for (int base = 0; base < deg; base += 64) {
            float a0 = -1e30f, a1 = -1e30f, a2 = -1e30f, a3 = -1e30f;
            if (base + ln < deg) logits(r0 + base + ln, a0, a1, a2, a3);
            m0 = fmaxf(m0, a0); m1 = fmaxf(m1, a1); m2 = fmaxf(m2, a2); m3 = fmaxf(m3, a3);
        }
        #pragma unroll
        for (int o = 32; o; o >>= 1) {
            m0 = fmaxf(m0, __shfl_xor(m0, o)); m1 = fmaxf(m1, __shfl_xor(m1, o));
            m2 = fmaxf(m2, __shfl_xor(m2, o)); m3 = fmaxf(m3, __shfl_xor(m3, o));
        }
        float s0 = 0.f, s1 = 0.f, s2 = 0.f, s3 = 0.f;
        for (int base = 0; base < deg; base += 64) {
            float a0, a1, a2, a3;
            if (base + ln < deg) {
                logits(r0 + base + ln, a0, a1, a2, a3);
                s0 += __expf(a0 - m0); s1 += __expf(a1 - m1);
                s2 += __expf(a2 - m2); s3 += __expf(a3 - m3);
            }
        }
        #pragma unroll
        for (int o = 32; o; o >>= 1) {
            s0 += __shfl_xor(s0, o); s1 += __shfl_xor(s1, o);
            s2 += __shfl_xor(s2, o); s3 += __shfl_xor(s3, o);
        }
        sc0 = 0.25f / (s0 + 1e-9f); sc1 = 0.25f / (s1 + 1e-9f);
        sc2 = 0.25f / (s2 + 1e-9f); sc3 = 0.25f / (s3 + 1e-9f);
        for (int base = 0; base < deg; base += 64) {
            int sidx = 0;
            float e0 = 0.f, e1 = 0.f, e2 = 0.f, e3 = 0.f;
            if (base + ln < deg) {
                float a0, a1, a2, a3;
                sidx = logits(r0 + base + ln, a0, a1, a2, a3);
                e0 = __expf(a0 - m0); e1 = __expf(a1 - m1);
                e2 = __expf(a2 - m2); e3 = __expf(a3 - m3);
            }
            int cnt = deg - base; if (cnt > 64) cnt = 64;
            gather_chunk<CH>(cnt, sidx, e0, e1, e2, e3, featb, ln, acc);
        }
    }

    // epilogue: per-head scale, head-mean via shuffles, residual + relu
    if (CH == 1) {
        float scl = ln < 16 ? sc0 : ln < 32 ? sc1 : ln < 48 ? sc2 : sc3;
        float t[8];
        #pragma unroll
        for (int i = 0; i < 8; ++i) {
            float v = acc[0][i] * scl;
            v += __shfl_xor(v, 16);
            v += __shfl_xor(v, 32);
            t[i] = v;
        }
        if (ln < 16) {
            int d0 = ln * 8;
            const float* yr = yres + (size_t)n * D + d0;
            float4 ya = *(const float4*)yr;
            float4 yb = *(const float4*)(yr + 4);
            float o[8];
            o[0] = fmaxf(ya.x + t[0], 0.f); o[1] = fmaxf(ya.y + t[1], 0.f);
            o[2] = fmaxf(ya.z + t[2], 0.f); o[3] = fmaxf(ya.w + t[3], 0.f);
            o[4] = fmaxf(yb.x + t[4], 0.f); o[5] = fmaxf(yb.y + t[5], 0.f);
            o[6] = fmaxf(yb.z + t[6], 0.f); o[7] = fmaxf(yb.w + t[7], 0.f);
            if (WRITE_BF) {
                uint4 pk;
                pk.x = (unsigned short)f2b(o[0]) | ((unsigned)(unsigned short)f2b(o[1]) << 16);
                pk.y = (unsigned short)f2b(o[2]) | ((unsigned)(unsigned short)f2b(o[3]) << 16);
                pk.z = (unsigned short)f2b(o[4]) | ((unsigned)(unsigned short)f2b(o[5]) << 16);
                pk.w = (unsigned short)f2b(o[6]) | ((unsigned)(unsigned short)f2b(o[7]) << 16);
                *(uint4*)(ybf + (size_t)n * D + d0) = pk;
            } else {
                float4 oa, ob;
                oa.x = o[0]; oa.y = o[1]; oa.z = o[2]; oa.w = o[3];
                ob.x = o[4]; ob.y = o[5]; ob.z = o[6]; ob.w = o[7];
                *(float4*)(yout + (size_t)n * D + d0) = oa;
                *(float4*)(yout + (size_t)n * D + d0 + 4) = ob;
            }
        }
    } else {
        float scA = ln < 32 ? sc0 : sc1;
        float scB = ln < 32 ? sc2 : sc3;
        float t[8];
        #pragma unroll
        for (int i = 0; i < 8; ++i) {
            float v = acc[0][i] * scA + acc[1][i] * scB;
            v += __shfl_xor(v, 32);
            t[i] = v;
        }
        if (ln < 32) {
            int d0 = ln * 8;
            const float* yr = yres + (size_t)n * D + d0;
            float4 ya = *(const float4*)yr;
            float4 yb = *(const float4*)(yr + 4);
            float o[8];
            o[0] = fmaxf(ya.x + t[0], 0.f); o[1] = fmaxf(ya.y + t[1], 0.f);
            o[2] = fmaxf(ya.z + t[2], 0.f); o[3] = fmaxf(ya.w + t[3], 0.f);
            o[4] = fmaxf(yb.x + t[4], 0.f); o[5] = fmaxf(yb.y + t[5], 0.f);
            o[6] = fmaxf(yb.z + t[6], 0.f); o[7] = fmaxf(yb.w + t[7], 0.f);
            if (WRITE_BF) {
                uint4 pk;
                pk.x = (unsigned short)f2b(o[0]) | ((unsigned)(unsigned short)f2b(o[1]) << 16);
                pk.y = (unsigned short)f2b(o[2]) | ((unsigned)(unsigned short)f2b(o[3]) << 16);
                pk.z = (unsigned short)f2b(o[4]) | ((unsigned)(unsigned short)f2b(o[5]) << 16);
                pk.w = (unsigned short)f2b(o[6]) | ((unsigned)(unsigned short)f2b(o[7]) << 16);
                *(uint4*)(ybf + (size_t)n * D + d0) = pk;
            } else {
                float4 oa, ob;
                oa.x = o[0]; oa.y = o[1]; oa.z = o[2]; oa.w = o[3];
                ob.x = o[4]; ob.y = o[5]; ob.z = o[6]; ob.w = o[7];
                *(float4*)(yout + (size_t)n * D + d0) = oa;
                *(float4*)(yout + (size_t)n * D + d0 + 4) = ob;
            }
        }
    }
}

// ---------------------------------------------------------------- host side
extern "C" void kernel_launch(void* const* d_in, const int* in_sizes, int n_in,
                              void* d_out, int out_size, void* d_ws, size_t ws_size,
                              hipStream_t stream) {
    const float* node_feats = (const float*)d_in[0];
    const float* edge_feats = (const float*)d_in[1];
    const int*   src        = (const int*)d_in[2];
    const int*   dst        = (const int*)d_in[3];
    const float* W1   = (const float*)d_in[4];
    const float* We1  = (const float*)d_in[5];
    const float* al1  = (const float*)d_in[6];
    const float* ar1  = (const float*)d_in[7];
    const float* ae1  = (const float*)d_in[8];
    const float* res1 = (const float*)d_in[9];
    const float* W2   = (const float*)d_in[10];
    const float* al2  = (const float*)d_in[11];
    const float* ar2  = (const float*)d_in[12];
    const float* res2 = (const float*)d_in[13];
    const float* W3   = (const float*)d_in[14];
    const float* al3  = (const float*)d_in[15];
    const float* ar3  = (const float*)d_in[16];
    const float* res3 = (const float*)d_in[17];
    const float* W4   = (const float*)d_in[18];
    const float* al4  = (const float*)d_in[19];
    const float* ar4  = (const float*)d_in[20];
    const float* res4 = (const float*)d_in[21];

    char* ws = (char*)d_ws;
    auto alloc = [&](size_t bytes) -> char* {
        char* p = ws;
        ws += (bytes + 255) & ~(size_t)255;
        return p;
    };
    int*   counts  = (int*)alloc((size_t)NN * 4);
    int*   offsets = (int*)alloc((size_t)(NN + 1) * 4);
    int*   cursor  = (int*)alloc((size_t)(NN + 1) * 4);
    int*   ssrc    = (int*)alloc((size_t)EE * 4);
    short* featb   = (short*)alloc((size_t)NN * 1024 * 2);
    float* xA      = (float*)alloc((size_t)NN * 128 * 4);
    short* xb      = (short*)alloc((size_t)NN * 128 * 2);
    float* elr     = (float*)alloc((size_t)NN * 8 * 4);   // [n][0..3]=el, [4..7]=er
    float* extra   = (float*)alloc((size_t)EE * 4 * 4);
    float* vbuf    = (float*)alloc(1024);
    short* Wc1     = (short*)alloc((size_t)704 * 128 * 2);
    short* Wc2     = (short*)alloc((size_t)704 * 128 * 2);
    short* Wc3     = (short*)alloc((size_t)704 * 128 * 2);
    short* Wc4     = (short*)alloc((size_t)1344 * 128 * 2);

    // ------- one prep kernel: transposes + wa + v + input cast + counts zero
    PrepParams P;
    P.tsrc[0] = W1;   P.tdst[0] = Wc1;              P.tN[0] = 512;
    P.tsrc[1] = W2;   P.tdst[1] = Wc2;              P.tN[1] = 512;
    P.tsrc[2] = W3;   P.tdst[2] = Wc3;              P.tN[2] = 512;
    P.tsrc[3] = W4;   P.tdst[3] = Wc4;              P.tN[3] = 1024;
    P.tsrc[4] = res1; P.tdst[4] = Wc1 + 512 * 128;  P.tN[4] = 128;
    P.tsrc[5] = res2; P.tdst[5] = Wc2 + 512 * 128;  P.tN[5] = 128;
    P.tsrc[6] = res3; P.tdst[6] = Wc3 + 512 * 128;  P.tN[6] = 128;
    P.tsrc[7] = res4; P.tdst[7] = Wc4 + 1024 * 128; P.tN[7] = 256;
    P.tcum[0] = 0;
    for (int i = 0; i < 8; ++i) P.tcum[i + 1] = P.tcum[i] + P.tN[i] * 128;
    P.W[0] = W1; P.W[1] = W2; P.W[2] = W3; P.W[3] = W4;
    P.al[0] = al1; P.al[1] = al2; P.al[2] = al3; P.al[3] = al4;
    P.ar[0] = ar1; P.ar[1] = ar2; P.ar[2] = ar3; P.ar[3] = ar4;
    P.Wc[0] = Wc1; P.Wc[1] = Wc2; P.Wc[2] = Wc3; P.Wc[3] = Wc4;
    P.Dl[0] = 128; P.Dl[1] = 128; P.Dl[2] = 128; P.Dl[3] = 256;
    P.base[0] = 640; P.base[1] = 640; P.base[2] = 640; P.base[3] = 1280;
    P.We1 = We1; P.ae1 = ae1; P.vbuf = vbuf;
    P.node_feats = node_feats; P.xb = xb;
    P.counts = counts;
    int bT = (P.tcum[8] + 255) / 256;     // 1664
    P.bV = bT; P.bWA = bT + 1; P.bC = bT + 9;
    P.bZ = P.bC + (NN * 128 + 255) / 256;
    int nblk = P.bZ + (NN + 255) / 256;
    prep_kernel<<<nblk, 256, 0, stream>>>(P);

    // ------- CSR build (+ fused layer-1 edge-extra)
    hist_kernel<<<(EE + 255) / 256, 256, 0, stream>>>(dst, counts, EE);
    scan_kernel<<<1, 256, 0, stream>>>(counts, offsets, cursor, NN);
    fill_extra<<<(EE + 255) / 256, 256, 0, stream>>>(src, dst, cursor, edge_feats,
                                                     vbuf, ssrc, extra, EE);

    float* out = (float*)d_out;
    dim3 g128(11, (NN + 63) / 64);   // 704/64
    dim3 g256(21, (NN + 63) / 64);   // 1344/64
    int gw = NN / 4;                 // 2500 blocks, 1 wave per node

    // ---- layer 1
    gemm_fused<128><<<g128, 256, 0, stream>>>(xb, Wc1, featb, xA, elr, NN);
    gat_wave<128, true, true><<<gw, 256, 0, stream>>>(featb, elr, extra, ssrc, offsets, xA, nullptr, xb);
    // ---- layer 2
    gemm_fused<128><<<g128, 256, 0, stream>>>(xb, Wc2, featb, xA, elr, NN);
    gat_wave<128, false, true><<<gw, 256, 0, stream>>>(featb, elr, nullptr, ssrc, offsets, xA, nullptr, xb);
    // ---- layer 3
    gemm_fused<128><<<g128, 256, 0, stream>>>(xb, Wc3, featb, xA, elr, NN);
    gat_wave<128, false, true><<<gw, 256, 0, stream>>>(featb, elr, nullptr, ssrc, offsets, xA, nullptr, xb);
    // ---- layer 4
    gemm_fused<256><<<g256, 256, 0, stream>>>(xb, Wc4, featb, out, elr, NN);
    gat_wave<256, false, false><<<gw, 256, 0, stream>>>(featb, elr, nullptr, ssrc, offsets, out, out, nullptr);
}

// Round 6
// 382.945 us; speedup vs baseline: 1.6237x; 1.1439x over previous
//
#include <hip/hip_runtime.h>

#define NN 10000
#define EE 160000

typedef __attribute__((ext_vector_type(8))) short bf16x8;
typedef __attribute__((ext_vector_type(4))) float f32x4;

__device__ __forceinline__ float b2f(unsigned short s) {
    union { unsigned u; float f; } v; v.u = ((unsigned)s) << 16; return v.f;
}
__device__ __forceinline__ short f2b(float f) {
    union { float f; unsigned u; } v; v.f = f;
    unsigned r = v.u + 0x7FFF + ((v.u >> 16) & 1);  // RNE
    return (short)(r >> 16);
}

// ---------------------------------------------------------------- CSR build
__global__ __launch_bounds__(256) void hist_kernel(const int* __restrict__ dst,
                                                   int* __restrict__ counts, int E) {
    int e = blockIdx.x * 256 + threadIdx.x;
    if (e < E) atomicAdd(&counts[dst[e]], 1);
}

// LDS-staged single-block scan: coalesced loads/stores, serial work only on LDS
__global__ __launch_bounds__(256) void scan_kernel(const int* __restrict__ counts,
                                                   int* __restrict__ off,
                                                   int* __restrict__ cur, int n) {
    __shared__ int buf[NN];
    __shared__ int part[256];
    int tid = threadIdx.x;
    for (int j = tid; j < n; j += 256) buf[j] = counts[j];
    __syncthreads();
    int chunk = (n + 255) / 256;
    int lo = tid * chunk; if (lo > n) lo = n;
    int hi = lo + chunk;  if (hi > n) hi = n;
    int s = 0;
    for (int i = lo; i < hi; ++i) s += buf[i];
    part[tid] = s;
    __syncthreads();
    for (int o = 1; o < 256; o <<= 1) {
        int v = (tid >= o) ? part[tid - o] : 0;
        __syncthreads();
        part[tid] += v;
        __syncthreads();
    }
    int run = (tid == 0) ? 0 : part[tid - 1];
    for (int i = lo; i < hi; ++i) { int c = buf[i]; buf[i] = run; run += c; }
    __syncthreads();
    for (int j = tid; j < n; j += 256) { int v = buf[j]; off[j] = v; cur[j] = v; }
    if (tid == 255) off[n] = part[255];
}

// fill + layer-1 edge-extra fused: writes ssrc[p] and extra[p] directly
__global__ __launch_bounds__(256) void fill_extra(const int* __restrict__ src,
                                                  const int* __restrict__ dst,
                                                  int* __restrict__ cur,
                                                  const float* __restrict__ ef,
                                                  const float* __restrict__ vbuf,
                                                  int* __restrict__ ssrc,
                                                  float* __restrict__ extra, int E) {
    __shared__ float vs[256];
    vs[threadIdx.x] = vbuf[threadIdx.x];
    __syncthreads();
    int e = blockIdx.x * 256 + threadIdx.x;
    if (e >= E) return;
    int p = atomicAdd(&cur[dst[e]], 1);
    ssrc[p] = src[e];
    float a0 = 0.f, a1 = 0.f, a2 = 0.f, a3 = 0.f;
    const float4* e4 = (const float4*)(ef + (size_t)e * 64);
    #pragma unroll
    for (int c = 0; c < 16; ++c) {
        float4 x = e4[c];
        int b = c * 16;
        a0 += x.x * vs[b + 0] + x.y * vs[b + 4] + x.z * vs[b + 8] + x.w * vs[b + 12];
        a1 += x.x * vs[b + 1] + x.y * vs[b + 5] + x.z * vs[b + 9] + x.w * vs[b + 13];
        a2 += x.x * vs[b + 2] + x.y * vs[b + 6] + x.z * vs[b + 10] + x.w * vs[b + 14];
        a3 += x.x * vs[b + 3] + x.y * vs[b + 7] + x.z * vs[b + 11] + x.w * vs[b + 15];
    }
    float4 o; o.x = a0; o.y = a1; o.z = a2; o.w = a3;
    *(float4*)(extra + (size_t)p * 4) = o;
}

// --------------------------- one prep kernel, all branches wave-parallel
struct PrepParams {
    const float* tsrc[8];
    short* tdst[8];
    int tN[8];
    int tshift[8];     // log2(tN)
    int tcum4[9];      // cumulative float4 counts
    const float* W[4]; const float* al[4]; const float* ar[4];
    short* Wc[4]; int Dl[4]; int base[4];
    const float* We1; const float* ae1; float* vbuf;
    const float* node_feats; short* xb;
    int* counts;
    int bWA, bV, bC, bZ;
};
__global__ __launch_bounds__(256) void prep_kernel(PrepParams P) {
    int blk = blockIdx.x, tid = threadIdx.x;
    if (blk < P.bWA) {
        // transpose W[128,N]f32 -> Wt[N,128]bf16; coalesced float4 reads
        int t = blk * 256 + tid;            // vec4 index
        if (t >= P.tcum4[8]) return;
        int i = 0;
        #pragma unroll
        for (int j = 1; j < 8; ++j) i += (t >= P.tcum4[j]);
        int local = t - P.tcum4[i];
        int N = P.tN[i], sh = P.tshift[i];
        int k = local >> (sh - 2);
        int nq = local & ((N >> 2) - 1);
        float4 v = *(const float4*)(P.tsrc[i] + (size_t)k * N + nq * 4);
        short* d = P.tdst[i] + (size_t)nq * 4 * 128 + k;
        d[0] = f2b(v.x); d[128] = f2b(v.y); d[256] = f2b(v.z); d[384] = f2b(v.w);
    } else if (blk < P.bV) {
        // wa columns: one wave per (k,h); coalesced row reads + shuffle reduce
        int bl = blk - P.bWA;               // 0..511
        int l = bl >> 7, within = bl & 127;
        int wv = tid >> 6, ln = tid & 63;
        int wid = within * 4 + wv;          // 0..511
        int k = wid >> 2, h = wid & 3;
        int D = P.Dl[l];
        const float* w = P.W[l] + ((size_t)k * 4 + h) * D;
        const float* a = P.al[l] + (size_t)h * D;
        const float* r = P.ar[l] + (size_t)h * D;
        float sa, sr;
        if (D == 128) {
            float2 w2 = ((const float2*)w)[ln];
            float2 a2 = ((const float2*)a)[ln];
            float2 r2 = ((const float2*)r)[ln];
            sa = w2.x * a2.x + w2.y * a2.y;
            sr = w2.x * r2.x + w2.y * r2.y;
        } else {
            float4 w4 = ((const float4*)w)[ln];
            float4 a4 = ((const float4*)a)[ln];
            float4 r4 = ((const float4*)r)[ln];
            sa = w4.x * a4.x + w4.y * a4.y + w4.z * a4.z + w4.w * a4.w;
            sr = w4.x * r4.x + w4.y * r4.y + w4.z * r4.z + w4.w * r4.w;
        }
        #pragma unroll
        for (int o = 32; o; o >>= 1) { sa += __shfl_xor(sa, o); sr += __shfl_xor(sr, o); }
        if (ln == 0) {
            P.Wc[l][(size_t)(P.base[l] + h) * 128 + k]     = f2b(sa);
            P.Wc[l][(size_t)(P.base[l] + 4 + h) * 128 + k] = f2b(sr);
        }
    } else if (blk < P.bC) {
        // v[i,h] = sum_d We[i,h,d]*ae[h,d]; one wave per i, loop h
        int bl = blk - P.bV;                // 0..15
        int wv = tid >> 6, ln = tid & 63;
        int i = bl * 4 + wv;                // 0..63
        #pragma unroll
        for (int h = 0; h < 4; ++h) {
            const float* w = P.We1 + ((size_t)i * 4 + h) * 128;
            const float* a = P.ae1 + (size_t)h * 128;
            float2 w2 = ((const float2*)w)[ln];
            float2 a2 = ((const float2*)a)[ln];
            float s = w2.x * a2.x + w2.y * a2.y;
            #pragma unroll
            for (int o = 32; o; o >>= 1) s += __shfl_xor(s, o);
            if (ln == 0) P.vbuf[i * 4 + h] = s;
        }
    } else if (blk < P.bZ) {
        // cast node_feats -> bf16, float4 -> packed bf16x4
        int t = (blk - P.bC) * 256 + tid;   // vec4 idx; total NN*32 = 320000
        if (t < NN * 32) {
            float4 v = ((const float4*)P.node_feats)[t];
            uint2 pk;
            pk.x = (unsigned short)f2b(v.x) | ((unsigned)(unsigned short)f2b(v.y) << 16);
            pk.y = (unsigned short)f2b(v.z) | ((unsigned)(unsigned short)f2b(v.w) << 16);
            ((uint2*)P.xb)[t] = pk;
        }
    } else {
        // zero counts (int4)
        int t = (blk - P.bZ) * 256 + tid;
        if (t < NN / 4) ((int4*)P.counts)[t] = make_int4(0, 0, 0, 0);
    }
}

// --------------------------------- fused GEMM: feat (bf16) + res (f32) + el/er
template <int D>
__global__ __launch_bounds__(256) void gemm_fused(const short* __restrict__ A,
                                                  const short* __restrict__ Bt,
                                                  short* __restrict__ featb,
                                                  float* __restrict__ y,
                                                  float* __restrict__ elr,
                                                  int M) {
    constexpr int HD = 4 * D;
    int wave = threadIdx.x >> 6, lane = threadIdx.x & 63;
    int m0 = blockIdx.y * 64;
    int n0 = blockIdx.x * 64 + wave * 16;
    int r = lane & 15, quad = lane >> 4;
    f32x4 acc[4] = {};
    const short* bp = Bt + (size_t)(n0 + r) * 128 + quad * 8;
    #pragma unroll
    for (int k0 = 0; k0 < 128; k0 += 32) {
        bf16x8 bfrag = *(const bf16x8*)(bp + k0);
        #pragma unroll
        for (int mt = 0; mt < 4; ++mt) {
            int gm = m0 + mt * 16 + r;
            bf16x8 afrag = {};
            if (gm < M) afrag = *(const bf16x8*)(A + (size_t)gm * 128 + k0 + quad * 8);
            acc[mt] = __builtin_amdgcn_mfma_f32_16x16x32_bf16(afrag, bfrag, acc[mt], 0, 0, 0);
        }
    }
    int col = n0 + r;
    #pragma unroll
    for (int mt = 0; mt < 4; ++mt) {
        #pragma unroll
        for (int rr = 0; rr < 4; ++rr) {
            int gm = m0 + mt * 16 + quad * 4 + rr;
            if (gm >= M) continue;
            float v = acc[mt][rr];
            if (col < HD)              featb[(size_t)gm * HD + col] = f2b(v);
            else if (col < HD + D)     y[(size_t)gm * D + (col - HD)] = v;
            else if (col < HD + D + 8) elr[(size_t)gm * 8 + (col - HD - D)] = v;
        }
    }
}

// ------------------------------------------------- wave-per-node fused GAT
__device__ __forceinline__ void accum8(float* a, uint4 v, float w) {
    a[0] += w * b2f((unsigned short)(v.x & 0xFFFF));
    a[1] += w * b2f((unsigned short)(v.x >> 16));
    a[2] += w * b2f((unsigned short)(v.y & 0xFFFF));
    a[3] += w * b2f((unsigned short)(v.y >> 16));
    a[4] += w * b2f((unsigned short)(v.z & 0xFFFF));
    a[5] += w * b2f((unsigned short)(v.z >> 16));
    a[6] += w * b2f((unsigned short)(v.w & 0xFFFF));
    a[7] += w * b2f((unsigned short)(v.w >> 16));
}

template <int CH>
__device__ __forceinline__ void gather_chunk(int cnt, int sidx,
                                             float e0, float e1, float e2, float e3,
                                             const short* __restrict__ featb, int ln,
                                             float acc[CH][8]) {
    constexpr int HD = CH * 512;
    const short* base = featb + ln * 8;
    int j = 0;
    for (; j + 2 <= cnt; j += 2) {
        int sA = __shfl(sidx, j), sB = __shfl(sidx, j + 1);
        float wA0 = __shfl(e0, j), wA1 = __shfl(e1, j), wA2 = __shfl(e2, j), wA3 = __shfl(e3, j);
        float wB0 = __shfl(e0, j + 1), wB1 = __shfl(e1, j + 1), wB2 = __shfl(e2, j + 1), wB3 = __shfl(e3, j + 1);
        const short* fA = base + (size_t)sA * HD;
        const short* fB = base + (size_t)sB * HD;
        uint4 vA[CH], vB[CH];
        #pragma unroll
        for (int c = 0; c < CH; ++c) { vA[c] = *(const uint4*)(fA + c * 512); vB[c] = *(const uint4*)(fB + c * 512); }
        #pragma unroll
        for (int c = 0; c < CH; ++c) {
            float wA, wB;
            if (CH == 1) {
                wA = ln < 16 ? wA0 : ln < 32 ? wA1 : ln < 48 ? wA2 : wA3;
                wB = ln < 16 ? wB0 : ln < 32 ? wB1 : ln < 48 ? wB2 : wB3;
            } else {
                wA = (c == 0) ? (ln < 32 ? wA0 : wA1) : (ln < 32 ? wA2 : wA3);
                wB = (c == 0) ? (ln < 32 ? wB0 : wB1) : (ln < 32 ? wB2 : wB3);
            }
            accum8(acc[c], vA[c], wA);
            accum8(acc[c], vB[c], wB);
        }
    }
    if (j < cnt) {
        int sA = __shfl(sidx, j);
        float wA0 = __shfl(e0, j), wA1 = __shfl(e1, j), wA2 = __shfl(e2, j), wA3 = __shfl(e3, j);
        const short* fA = base + (size_t)sA * HD;
        #pragma unroll
        for (int c = 0; c < CH; ++c) {
            uint4 vA = *(const uint4*)(fA + c * 512);
            float wA;
            if (CH == 1) wA = ln < 16 ? wA0 : ln < 32 ? wA1 : ln < 48 ? wA2 : wA3;
            else         wA = (c == 0) ? (ln < 32 ? wA0 : wA1) : (ln < 32 ? wA2 : wA3);
            accum8(acc[c], vA, wA);
        }
    }
}

template <int D, bool HAS_EXTRA, bool WRITE_BF>
__global__ __launch_bounds__(256) void gat_wave(const short* __restrict__ featb,
                                                const float* __restrict__ elr,
                                                const float* __restrict__ extra,
                                                const int* __restrict__ ssrc,
                                                const int* __restrict__ off,
                                                const float* __restrict__ yres,
                                                float* __restrict__ yout,
                                                short* __restrict__ ybf) {
    constexpr int HD = 4 * D;
    constexpr int CH = HD / 512;
    int wv = threadIdx.x >> 6, ln = threadIdx.x & 63;
    int n = blockIdx.x * 4 + wv;        // NN % 4 == 0
    int r0 = off[n], deg = off[n + 1] - r0;

    float4 erv = *(const float4*)(elr + (size_t)n * 8 + 4);

    float acc[CH][8];
    #pragma unroll
    for (int c = 0; c < CH; ++c)
        #pragma unroll
        for (int i = 0; i < 8; ++i) acc[c][i] = 0.f;

    float sc0, sc1, sc2, sc3;

    auto logits = [&](int idx, float& a0, float& a1, float& a2, float& a3) {
        int s = ssrc[idx];
        float4 elv = *(const float4*)(elr + (size_t)s * 8);
        a0 = elv.x + erv.x; a1 = elv.y + erv.y; a2 = elv.z + erv.z; a3 = elv.w + erv.w;
        if (HAS_EXTRA) {
            float4 exv = *(const float4*)(extra + (size_t)idx * 4);
            a0 += exv.x; a1 += exv.y; a2 += exv.z; a3 += exv.w;
        }
        a0 = a0 > 0.f ? a0 : 0.2f * a0;
        a1 = a1 > 0.f ? a1 : 0.2f * a1;
        a2 = a2 > 0.f ? a2 : 0.2f * a2;
        a3 = a3 > 0.f ? a3 : 0.2f * a3;
        return s;
    };

    if (deg <= 64) {
        int sidx = 0;
        float a0 = -1e30f, a1 = -1e30f, a2 = -1e30f, a3 = -1e30f;
        if (ln < deg) sidx = logits(r0 + ln, a0, a1, a2, a3);
        float m0 = a0, m1 = a1, m2 = a2, m3 = a3;
        #pragma unroll
        for (int o = 32; o; o >>= 1) {
            m0 = fmaxf(m0, __shfl_xor(m0, o)); m1 = fmaxf(m1, __shfl_xor(m1, o));
            m2 = fmaxf(m2, __shfl_xor(m2, o)); m3 = fmaxf(m3, __shfl_xor(m3, o));
        }
        float e0 = 0.f, e1 = 0.f, e2 = 0.f, e3 = 0.f;
        if (ln < deg) {
            e0 = __expf(a0 - m0); e1 = __expf(a1 - m1);
            e2 = __expf(a2 - m2); e3 = __expf(a3 - m3);
        }
        float s0 = e0, s1 = e1, s2 = e2, s3 = e3;
        #pragma unroll
        for (int o = 32; o; o >>= 1) {
            s0 += __shfl_xor(s0, o); s1 += __shfl_xor(s1, o);
            s2 += __shfl_xor(s2, o); s3 += __shfl_xor(s3, o);
        }
        sc0 = 0.25f / (s0 + 1e-9f); sc1 = 0.25f / (s1 + 1e-9f);
        sc2 = 0.25f / (s2 + 1e-9f); sc3 = 0.25f / (s3 + 1e-9f);
        gather_chunk<CH>(deg, sidx, e0, e1, e2, e3, featb, ln, acc);
    } else {
        // never expected (P(deg>64) ~ 0), kept for correctness
        float m0 = -1e30f, m1 = -1e30f, m2 = -1e30f, m3 = -1e30f;
        for (int base = 0; base < deg; base += 64) {
            float a0 = -1e30f, a1 = -1e30f, a2 = -1e30f, a3 = -1e30f;
            if (base + ln < deg) logits(r0 + base + ln, a0, a1, a2, a3);
            m0 = fmaxf(m0, a0); m1 = fmaxf(m1, a1); m2 = fmaxf(m2, a2); m3 = fmaxf(m3, a3);
        }
        #pragma unroll
        for (int o = 32; o; o >>= 1) {
            m0 = fmaxf(m0, __shfl_xor(m0, o)); m1 = fmaxf(m1, __shfl_xor(m1, o));
            m2 = fmaxf(m2, __shfl_xor(m2, o)); m3 = fmaxf(m3, __shfl_xor(m3, o));
        }
        float s0 = 0.f, s1 = 0.f, s2 = 0.f, s3 = 0.f;
        for (int base = 0; base < deg; base += 64) {
            float a0, a1, a2, a3;
            if (base + ln < deg) {
                logits(r0 + base + ln, a0, a1, a2, a3);
                s0 += __expf(a0 - m0); s1 += __expf(a1 - m1);
                s2 += __expf(a2 - m2); s3 += __expf(a3 - m3);
            }
        }
        #pragma unroll
        for (int o = 32; o; o >>= 1) {
            s0 += __shfl_xor(s0, o); s1 += __shfl_xor(s1, o);
            s2 += __shfl_xor(s2, o); s3 += __shfl_xor(s3, o);
        }
        sc0 = 0.25f / (s0 + 1e-9f); sc1 = 0.25f / (s1 + 1e-9f);
        sc2 = 0.25f / (s2 + 1e-9f); sc3 = 0.25f / (s3 + 1e-9f);
        for (int base = 0; base < deg; base += 64) {
            int sidx = 0;
            float e0 = 0.f, e1 = 0.f, e2 = 0.f, e3 = 0.f;
            if (base + ln < deg) {
                float a0, a1, a2, a3;
                sidx = logits(r0 + base + ln, a0, a1, a2, a3);
                e0 = __expf(a0 - m0); e1 = __expf(a1 - m1);
                e2 = __expf(a2 - m2); e3 = __expf(a3 - m3);
            }
            int cnt = deg - base; if (cnt > 64) cnt = 64;
            gather_chunk<CH>(cnt, sidx, e0, e1, e2, e3, featb, ln, acc);
        }
    }

    // epilogue: per-head scale, head-mean via shuffles, residual + relu
    if (CH == 1) {
        float scl = ln < 16 ? sc0 : ln < 32 ? sc1 : ln < 48 ? sc2 : sc3;
        float t[8];
        #pragma unroll
        for (int i = 0; i < 8; ++i) {
            float v = acc[0][i] * scl;
            v += __shfl_xor(v, 16);
            v += __shfl_xor(v, 32);
            t[i] = v;
        }
        if (ln < 16) {
            int d0 = ln * 8;
            const float* yr = yres + (size_t)n * D + d0;
            float4 ya = *(const float4*)yr;
            float4 yb = *(const float4*)(yr + 4);
            float o[8];
            o[0] = fmaxf(ya.x + t[0], 0.f); o[1] = fmaxf(ya.y + t[1], 0.f);
            o[2] = fmaxf(ya.z + t[2], 0.f); o[3] = fmaxf(ya.w + t[3], 0.f);
            o[4] = fmaxf(yb.x + t[4], 0.f); o[5] = fmaxf(yb.y + t[5], 0.f);
            o[6] = fmaxf(yb.z + t[6], 0.f); o[7] = fmaxf(yb.w + t[7], 0.f);
            if (WRITE_BF) {
                uint4 pk;
                pk.x = (unsigned short)f2b(o[0]) | ((unsigned)(unsigned short)f2b(o[1]) << 16);
                pk.y = (unsigned short)f2b(o[2]) | ((unsigned)(unsigned short)f2b(o[3]) << 16);
                pk.z = (unsigned short)f2b(o[4]) | ((unsigned)(unsigned short)f2b(o[5]) << 16);
                pk.w = (unsigned short)f2b(o[6]) | ((unsigned)(unsigned short)f2b(o[7]) << 16);
                *(uint4*)(ybf + (size_t)n * D + d0) = pk;
            } else {
                float4 oa, ob;
                oa.x = o[0]; oa.y = o[1]; oa.z = o[2]; oa.w = o[3];
                ob.x = o[4]; ob.y = o[5]; ob.z = o[6]; ob.w = o[7];
                *(float4*)(yout + (size_t)n * D + d0) = oa;
                *(float4*)(yout + (size_t)n * D + d0 + 4) = ob;
            }
        }
    } else {
        float scA = ln < 32 ? sc0 : sc1;
        float scB = ln < 32 ? sc2 : sc3;
        float t[8];
        #pragma unroll
        for (int i = 0; i < 8; ++i) {
            float v = acc[0][i] * scA + acc[1][i] * scB;
            v += __shfl_xor(v, 32);
            t[i] = v;
        }
        if (ln < 32) {
            int d0 = ln * 8;
            const float* yr = yres + (size_t)n * D + d0;
            float4 ya = *(const float4*)yr;
            float4 yb = *(const float4*)(yr + 4);
            float o[8];
            o[0] = fmaxf(ya.x + t[0], 0.f); o[1] = fmaxf(ya.y + t[1], 0.f);
            o[2] = fmaxf(ya.z + t[2], 0.f); o[3] = fmaxf(ya.w + t[3], 0.f);
            o[4] = fmaxf(yb.x + t[4], 0.f); o[5] = fmaxf(yb.y + t[5], 0.f);
            o[6] = fmaxf(yb.z + t[6], 0.f); o[7] = fmaxf(yb.w + t[7], 0.f);
            if (WRITE_BF) {
                uint4 pk;
                pk.x = (unsigned short)f2b(o[0]) | ((unsigned)(unsigned short)f2b(o[1]) << 16);
                pk.y = (unsigned short)f2b(o[2]) | ((unsigned)(unsigned short)f2b(o[3]) << 16);
                pk.z = (unsigned short)f2b(o[4]) | ((unsigned)(unsigned short)f2b(o[5]) << 16);
                pk.w = (unsigned short)f2b(o[6]) | ((unsigned)(unsigned short)f2b(o[7]) << 16);
                *(uint4*)(ybf + (size_t)n * D + d0) = pk;
            } else {
                float4 oa, ob;
                oa.x = o[0]; oa.y = o[1]; oa.z = o[2]; oa.w = o[3];
                ob.x = o[4]; ob.y = o[5]; ob.z = o[6]; ob.w = o[7];
                *(float4*)(yout + (size_t)n * D + d0) = oa;
                *(float4*)(yout + (size_t)n * D + d0 + 4) = ob;
            }
        }
    }
}

// ---------------------------------------------------------------- host side
extern "C" void kernel_launch(void* const* d_in, const int* in_sizes, int n_in,
                              void* d_out, int out_size, void* d_ws, size_t ws_size,
                              hipStream_t stream) {
    const float* node_feats = (const float*)d_in[0];
    const float* edge_feats = (const float*)d_in[1];
    const int*   src        = (const int*)d_in[2];
    const int*   dst        = (const int*)d_in[3];
    const float* W1   = (const float*)d_in[4];
    const float* We1  = (const float*)d_in[5];
    const float* al1  = (const float*)d_in[6];
    const float* ar1  = (const float*)d_in[7];
    const float* ae1  = (const float*)d_in[8];
    const float* res1 = (const float*)d_in[9];
    const float* W2   = (const float*)d_in[10];
    const float* al2  = (const float*)d_in[11];
    const float* ar2  = (const float*)d_in[12];
    const float* res2 = (const float*)d_in[13];
    const float* W3   = (const float*)d_in[14];
    const float* al3  = (const float*)d_in[15];
    const float* ar3  = (const float*)d_in[16];
    const float* res3 = (const float*)d_in[17];
    const float* W4   = (const float*)d_in[18];
    const float* al4  = (const float*)d_in[19];
    const float* ar4  = (const float*)d_in[20];
    const float* res4 = (const float*)d_in[21];

    char* ws = (char*)d_ws;
    auto alloc = [&](size_t bytes) -> char* {
        char* p = ws;
        ws += (bytes + 255) & ~(size_t)255;
        return p;
    };
    int*   counts  = (int*)alloc((size_t)NN * 4);
    int*   offsets = (int*)alloc((size_t)(NN + 1) * 4);
    int*   cursor  = (int*)alloc((size_t)(NN + 1) * 4);
    int*   ssrc    = (int*)alloc((size_t)EE * 4);
    short* featb   = (short*)alloc((size_t)NN * 1024 * 2);
    float* xA      = (float*)alloc((size_t)NN * 128 * 4);
    short* xb      = (short*)alloc((size_t)NN * 128 * 2);
    float* elr     = (float*)alloc((size_t)NN * 8 * 4);   // [n][0..3]=el, [4..7]=er
    float* extra   = (float*)alloc((size_t)EE * 4 * 4);
    float* vbuf    = (float*)alloc(1024);
    short* Wc1     = (short*)alloc((size_t)704 * 128 * 2);
    short* Wc2     = (short*)alloc((size_t)704 * 128 * 2);
    short* Wc3     = (short*)alloc((size_t)704 * 128 * 2);
    short* Wc4     = (short*)alloc((size_t)1344 * 128 * 2);

    // ------- one prep kernel: transposes + wa + v + input cast + counts zero
    PrepParams P;
    P.tsrc[0] = W1;   P.tdst[0] = Wc1;              P.tN[0] = 512;  P.tshift[0] = 9;
    P.tsrc[1] = W2;   P.tdst[1] = Wc2;              P.tN[1] = 512;  P.tshift[1] = 9;
    P.tsrc[2] = W3;   P.tdst[2] = Wc3;              P.tN[2] = 512;  P.tshift[2] = 9;
    P.tsrc[3] = W4;   P.tdst[3] = Wc4;              P.tN[3] = 1024; P.tshift[3] = 10;
    P.tsrc[4] = res1; P.tdst[4] = Wc1 + 512 * 128;  P.tN[4] = 128;  P.tshift[4] = 7;
    P.tsrc[5] = res2; P.tdst[5] = Wc2 + 512 * 128;  P.tN[5] = 128;  P.tshift[5] = 7;
    P.tsrc[6] = res3; P.tdst[6] = Wc3 + 512 * 128;  P.tN[6] = 128;  P.tshift[6] = 7;
    P.tsrc[7] = res4; P.tdst[7] = Wc4 + 1024 * 128; P.tN[7] = 256;  P.tshift[7] = 8;
    P.tcum4[0] = 0;
    for (int i = 0; i < 8; ++i) P.tcum4[i + 1] = P.tcum4[i] + P.tN[i] * 128 / 4;
    P.W[0] = W1; P.W[1] = W2; P.W[2] = W3; P.W[3] = W4;
    P.al[0] = al1; P.al[1] = al2; P.al[2] = al3; P.al[3] = al4;
    P.ar[0] = ar1; P.ar[1] = ar2; P.ar[2] = ar3; P.ar[3] = ar4;
    P.Wc[0] = Wc1; P.Wc[1] = Wc2; P.Wc[2] = Wc3; P.Wc[3] = Wc4;
    P.Dl[0] = 128; P.Dl[1] = 128; P.Dl[2] = 128; P.Dl[3] = 256;
    P.base[0] = 640; P.base[1] = 640; P.base[2] = 640; P.base[3] = 1280;
    P.We1 = We1; P.ae1 = ae1; P.vbuf = vbuf;
    P.node_feats = node_feats; P.xb = xb;
    P.counts = counts;
    P.bWA = (P.tcum4[8] + 255) / 256;         // 400
    P.bV  = P.bWA + 512;
    P.bC  = P.bV + 16;
    P.bZ  = P.bC + (NN * 32 + 255) / 256;     // +1250
    int nblk = P.bZ + (NN / 4 + 255) / 256;   // +10
    prep_kernel<<<nblk, 256, 0, stream>>>(P);

    // ------- CSR build (+ fused layer-1 edge-extra)
    hist_kernel<<<(EE + 255) / 256, 256, 0, stream>>>(dst, counts, EE);
    scan_kernel<<<1, 256, 0, stream>>>(counts, offsets, cursor, NN);
    fill_extra<<<(EE + 255) / 256, 256, 0, stream>>>(src, dst, cursor, edge_feats,
                                                     vbuf, ssrc, extra, EE);

    float* out = (float*)d_out;
    dim3 g128(11, (NN + 63) / 64);   // 704/64
    dim3 g256(21, (NN + 63) / 64);   // 1344/64
    int gw = NN / 4;                 // 2500 blocks, 1 wave per node

    // ---- layer 1
    gemm_fused<128><<<g128, 256, 0, stream>>>(xb, Wc1, featb, xA, elr, NN);
    gat_wave<128, true, true><<<gw, 256, 0, stream>>>(featb, elr, extra, ssrc, offsets, xA, nullptr, xb);
    // ---- layer 2
    gemm_fused<128><<<g128, 256, 0, stream>>>(xb, Wc2, featb, xA, elr, NN);
    gat_wave<128, false, true><<<gw, 256, 0, stream>>>(featb, elr, nullptr, ssrc, offsets, xA, nullptr, xb);
    // ---- layer 3
    gemm_fused<128><<<g128, 256, 0, stream>>>(xb, Wc3, featb, xA, elr, NN);
    gat_wave<128, false, true><<<gw, 256, 0, stream>>>(featb, elr, nullptr, ssrc, offsets, xA, nullptr, xb);
    // ---- layer 4
    gemm_fused<256><<<g256, 256, 0, stream>>>(xb, Wc4, featb, out, elr, NN);
    gat_wave<256, false, false><<<gw, 256, 0, stream>>>(featb, elr, nullptr, ssrc, offsets, out, out, nullptr);
}